// Round 10
// baseline (210.312 us; speedup 1.0000x reference)
//
#include <hip/hip_runtime.h>
#include <math.h>

typedef __attribute__((ext_vector_type(8))) short bf16x8;
typedef __attribute__((ext_vector_type(4))) float f32x4;

__device__ __forceinline__ unsigned short f2bf(float f) {
  unsigned u = __float_as_uint(f);
  u += 0x7fffu + ((u >> 16) & 1u);  // round-to-nearest-even
  return (unsigned short)(u >> 16);
}
__device__ __forceinline__ float bflo(unsigned u) { return __uint_as_float(u << 16); }
__device__ __forceinline__ float bfhi(unsigned u) { return __uint_as_float(u & 0xffff0000u); }

#define ACC8(U)                                           \
  a0 += bflo(U.x); a1 += bfhi(U.x); a2 += bflo(U.y); a3 += bfhi(U.y); \
  a4 += bflo(U.z); a5 += bfhi(U.z); a6 += bflo(U.w); a7 += bfhi(U.w)

// ================= CSR via two-level bucket binning =================
// Buckets of 128 nodes (NB = ceil(N/128) = 391 <= 512). packed edge =
// (d_local<<16)|src. Requires N <= 65536 — N = 50000 here.

constexpr int CB = 64;    // histogram blocks
constexpr int EB = 4096;  // edges per binning block

__global__ __launch_bounds__(256) void count_pack(const int* __restrict__ dst,
                                                  int* __restrict__ partial, int E,
                                                  const float* __restrict__ W1,
                                                  const float* __restrict__ W2,
                                                  const float* __restrict__ W3,
                                                  unsigned short* __restrict__ Wp1,
                                                  unsigned short* __restrict__ Wp2,
                                                  unsigned short* __restrict__ Wp3) {
  int tid = threadIdx.x;
  if (blockIdx.x < CB) {
    __shared__ int bkt[512];
    bkt[tid] = 0;
    bkt[tid + 256] = 0;
    __syncthreads();
    int E4 = E >> 2;
    const int4* d4 = (const int4*)dst;
    for (int i = blockIdx.x * 256 + tid; i < E4; i += CB * 256) {
      int4 d = d4[i];
      atomicAdd(&bkt[d.x >> 7], 1);
      atomicAdd(&bkt[d.y >> 7], 1);
      atomicAdd(&bkt[d.z >> 7], 1);
      atomicAdd(&bkt[d.w >> 7], 1);
    }
    if (blockIdx.x == 0 && tid < (E & 3)) atomicAdd(&bkt[dst[E4 * 4 + tid] >> 7], 1);
    __syncthreads();
    partial[blockIdx.x * 512 + tid] = bkt[tid];
    partial[blockIdx.x * 512 + tid + 256] = bkt[tid + 256];
    return;
  }
  int gid = (blockIdx.x - CB) * 256 + tid;
  const float* W;
  unsigned short* Wp;
  int t, NCTT, M, MV;
  if (gid < 1536) {            // W1: 4 ksteps * 6 coltiles * 64 lanes
    W = W1; Wp = Wp1; t = gid; NCTT = 6; M = 96; MV = 96;
  } else if (gid < 2688) {     // W2: 3 * 6 * 64
    W = W2; Wp = Wp2; t = gid - 1536; NCTT = 6; M = 96; MV = 96;
  } else if (gid < 3264) {     // W3: 3 * 3 * 64 (cols >= 40 zero-padded)
    W = W3; Wp = Wp3; t = gid - 2688; NCTT = 3; M = 40; MV = 40;
  } else {
    return;
  }
  int lane = t & 63;
  int frag = t >> 6;
  int s = frag / NCTT;
  int ct = frag - s * NCTT;
  int colv = ct * 16 + (lane & 15);
  int k0 = s * 32 + (lane >> 4) * 8;
  union { unsigned short s[8]; uint4 u; } pk;
#pragma unroll
  for (int j = 0; j < 8; ++j) {
    float v = (colv < MV) ? W[(k0 + j) * M + colv] : 0.f;
    pk.s[j] = f2bf(v);
  }
  ((uint4*)Wp)[t] = pk.u;
}

__global__ __launch_bounds__(256) void scan_kernel(const int* __restrict__ partial,
                                                   int* __restrict__ gstart,
                                                   int* __restrict__ gcur,
                                                   int* __restrict__ row_ptr,
                                                   int NB, int N, int E) {
  __shared__ int sm[512];
  int tid = threadIdx.x;
  int s0 = 0, s1 = 0;
#pragma unroll 8
  for (int i = 0; i < CB; ++i) {
    s0 += partial[i * 512 + tid];
    s1 += partial[i * 512 + tid + 256];
  }
  sm[tid] = s0;
  sm[tid + 256] = s1;
  __syncthreads();
  for (int off = 1; off < 512; off <<= 1) {
    int a0 = (tid >= off) ? sm[tid - off] : 0;
    int i1 = tid + 256;
    int a1 = (i1 >= off) ? sm[i1 - off] : 0;
    __syncthreads();
    sm[tid] += a0;
    sm[i1] += a1;
    __syncthreads();
  }
  int e0 = sm[tid] - s0;
  int e1 = sm[tid + 256] - s1;
  if (tid < NB) { gstart[tid] = e0; gcur[tid] = e0; }
  int b1 = tid + 256;
  if (b1 < NB) { gstart[b1] = e1; gcur[b1] = e1; }
  if (tid == 255) gstart[NB] = sm[511];
  if (tid == 0) row_ptr[N] = E;
}

// Dispatch 3: [0,NBIN) LDS-staged binning; [NBIN,..) gemm1 with packed Wp1.
__global__ __launch_bounds__(256) void bin_gemm1(const int* __restrict__ src,
                                                 const int* __restrict__ dst,
                                                 int* __restrict__ gcur,
                                                 int* __restrict__ packed, int E, int NB,
                                                 int NBIN, const float* __restrict__ x,
                                                 const unsigned short* __restrict__ Wp1,
                                                 unsigned short* __restrict__ Tb, int N) {
  __shared__ int lcnt[512];
  __shared__ int lstart[512];
  __shared__ int gbase[512];
  __shared__ int cur[512];
  __shared__ int stage[EB];
  int tid = threadIdx.x;
  if (blockIdx.x < NBIN) {
    lcnt[tid] = 0;
    lcnt[tid + 256] = 0;
    __syncthreads();
    int E4 = E >> 2;
    int base4 = blockIdx.x * (EB >> 2);
    int sv[16], dv[16];
    int nv = 0;
#pragma unroll
    for (int j = 0; j < 4; ++j) {
      int idx4 = base4 + j * 256 + tid;
      if (idx4 < E4 && idx4 < base4 + (EB >> 2)) {
        int4 s4 = ((const int4*)src)[idx4];
        int4 d4 = ((const int4*)dst)[idx4];
        sv[j * 4 + 0] = s4.x; dv[j * 4 + 0] = d4.x;
        sv[j * 4 + 1] = s4.y; dv[j * 4 + 1] = d4.y;
        sv[j * 4 + 2] = s4.z; dv[j * 4 + 2] = d4.z;
        sv[j * 4 + 3] = s4.w; dv[j * 4 + 3] = d4.w;
        nv = j * 4 + 4;
      }
    }
#pragma unroll
    for (int i = 0; i < 16; ++i)
      if (i < nv) atomicAdd(&lcnt[dv[i] >> 7], 1);
    bool last = (blockIdx.x == NBIN - 1);
    int tl = E & 3;
    if (last && tid == 0)
      for (int t = 0; t < tl; ++t) atomicAdd(&lcnt[dst[E4 * 4 + t] >> 7], 1);
    __syncthreads();
    lstart[tid] = lcnt[tid];
    lstart[tid + 256] = lcnt[tid + 256];
    __syncthreads();
    for (int off = 1; off < 512; off <<= 1) {
      int a0 = (tid >= off) ? lstart[tid - off] : 0;
      int i1 = tid + 256;
      int a1 = (i1 >= off) ? lstart[i1 - off] : 0;
      __syncthreads();
      lstart[tid] += a0;
      lstart[i1] += a1;
      __syncthreads();
    }
    int e0 = lstart[tid] - lcnt[tid];
    int e1 = lstart[tid + 256] - lcnt[tid + 256];
    __syncthreads();
    lstart[tid] = e0; cur[tid] = e0;
    lstart[tid + 256] = e1; cur[tid + 256] = e1;
    __syncthreads();
#pragma unroll
    for (int i = 0; i < 16; ++i)
      if (i < nv) {
        int b = dv[i] >> 7;
        int p = atomicAdd(&cur[b], 1);
        stage[p] = ((dv[i] & 127) << 16) | (sv[i] & 0xffff);
      }
    if (last && tid == 0)
      for (int t = 0; t < tl; ++t) {
        int d = dst[E4 * 4 + t], s = src[E4 * 4 + t];
        int p = atomicAdd(&cur[d >> 7], 1);
        stage[p] = ((d & 127) << 16) | (s & 0xffff);
      }
    if (lcnt[tid]) gbase[tid] = atomicAdd(&gcur[tid], lcnt[tid]);
    if (lcnt[tid + 256]) gbase[tid + 256] = atomicAdd(&gcur[tid + 256], lcnt[tid + 256]);
    __syncthreads();
    int meB = lstart[511] + lcnt[511];
    for (int i = tid; i < meB; i += 256) {
      int lo = 0, hi = 511;
      while (lo < hi) {
        int mid = (lo + hi + 1) >> 1;
        if (lstart[mid] <= i) lo = mid; else hi = mid - 1;
      }
      packed[gbase[lo] + (i - lstart[lo])] = stage[i];
    }
    return;
  }
  // ---- gemm1: 16 rows x 96 cols per wave, KSTEPS=4 ----
  int bx = blockIdx.x - NBIN;
  int wid = tid >> 6;
  int lane = tid & 63;
  int rt = bx * 4 + wid;
  if (rt * 16 >= N) return;
  int quad = lane >> 4;
  int lm = lane & 15;
  union BU { uint4 u; bf16x8 v; };
  f32x4 acc[6];
#pragma unroll
  for (int c = 0; c < 6; ++c) acc[c] = (f32x4){0.f, 0.f, 0.f, 0.f};
  int row = rt * 16 + lm;
  if (row >= N) row = N - 1;
  const uint4* wp4 = (const uint4*)Wp1;
#pragma unroll
  for (int s = 0; s < 4; ++s) {
    int k0 = s * 32 + quad * 8;
    const float* Af = x + (size_t)row * 128 + k0;
    float4 x0 = *(const float4*)(Af);
    float4 x1 = *(const float4*)(Af + 4);
    union { unsigned short s[8]; bf16x8 v; } au;
    au.s[0] = f2bf(x0.x); au.s[1] = f2bf(x0.y); au.s[2] = f2bf(x0.z); au.s[3] = f2bf(x0.w);
    au.s[4] = f2bf(x1.x); au.s[5] = f2bf(x1.y); au.s[6] = f2bf(x1.z); au.s[7] = f2bf(x1.w);
#pragma unroll
    for (int c = 0; c < 6; ++c) {
      BU bu;
      bu.u = wp4[(s * 6 + c) * 64 + lane];
      acc[c] = __builtin_amdgcn_mfma_f32_16x16x32_bf16(au.v, bu.v, acc[c], 0, 0, 0);
    }
  }
#pragma unroll
  for (int c = 0; c < 6; ++c) {
    int colv = c * 16 + lm;
#pragma unroll
    for (int r = 0; r < 4; ++r) {
      int orow = rt * 16 + quad * 4 + r;
      if (orow < N) Tb[(size_t)orow * 96 + colv] = f2bf(acc[c][r]);
    }
  }
}

// One block per 128-node bucket: local count -> local scan -> row_ptr + col.
__global__ __launch_bounds__(256) void build_local_csr(const int* __restrict__ packed,
                                                       const int* __restrict__ gstart,
                                                       int* __restrict__ row_ptr,
                                                       int* __restrict__ col, int N) {
  __shared__ int cnt[128];
  __shared__ int sm[128];
  int b = blockIdx.x, tid = threadIdx.x;
  int gs = gstart[b], ge = gstart[b + 1];
  int me = ge - gs;
  int node0 = b << 7;
  int RL = N - node0;
  if (RL > 128) RL = 128;
  if (tid < 128) cnt[tid] = 0;
  __syncthreads();
  for (int i = tid; i < me; i += 256) atomicAdd(&cnt[packed[gs + i] >> 16], 1);
  __syncthreads();
  if (tid < 128) sm[tid] = cnt[tid];
  __syncthreads();
  for (int off = 1; off < 128; off <<= 1) {
    int u = (tid >= off && tid < 128) ? sm[tid - off] : 0;
    __syncthreads();
    if (tid < 128) sm[tid] += u;
    __syncthreads();
  }
  if (tid < 128) {
    int excl = gs + sm[tid] - cnt[tid];
    cnt[tid] = excl;
    if (tid < RL) row_ptr[node0 + tid] = excl;
  }
  __syncthreads();
  for (int i = tid; i < me; i += 256) {
    int pk = packed[gs + i];
    int p = atomicAdd(&cnt[pk >> 16], 1);
    col[p] = pk & 0xffff;
  }
}

// ================= Fused aggregation + GEMM =================
// Block owns 64 nodes; col + row_ptr staged in LDS. Fast path (me <= CAP,
// ~16 sigma certain): branchless LDS-index loop unrolled x8 (8 VMEMs in
// flight/thread). Phase B: 4 waves x 16-row MFMA tiles; per-step B reload.

template <int NCT, int MOUT, int MVALID>
__global__ __launch_bounds__(256, 7) void fused_agg_gemm(
    const unsigned short* __restrict__ tin, const int* __restrict__ row_ptr,
    const int* __restrict__ col, const float* __restrict__ bias,
    const unsigned short* __restrict__ Wp, unsigned short* __restrict__ outp, int N) {
  constexpr int LST = 104;   // bf16 units per LDS row
  constexpr int CAP = 1536;
  __shared__ unsigned short sH[64 * LST];
  __shared__ int scol[CAP];
  __shared__ int srp[65];
  int tid = threadIdx.x;
  int node0 = blockIdx.x * 64;
  int nloc = N - node0;
  if (nloc > 64) nloc = 64;
  if (tid <= nloc) srp[tid] = row_ptr[node0 + tid];
  __syncthreads();
  int gs = srp[0];
  int me = srp[nloc] - gs;
  for (int i = tid; i < me && i < CAP; i += 256) scol[i] = col[gs + i];
  __syncthreads();
  bool fits = (me <= CAP);

  // ---- Phase A: aggregate 64 nodes x 12 chunks of 8 bf16 ----
#pragma unroll
  for (int it = 0; it < 3; ++it) {
    int u = tid + it * 256;
    int nl = u / 12;
    int c = u - nl * 12;
    if (nl < nloc) {
      int beg = srp[nl] - gs;
      int end = srp[nl + 1] - gs;
      const unsigned short* tc = tin + 8 * c;
      float a0 = 0.f, a1 = 0.f, a2 = 0.f, a3 = 0.f, a4 = 0.f, a5 = 0.f, a6 = 0.f, a7 = 0.f;
      if (fits) {
        int e = beg;
        for (; e + 7 < end; e += 8) {
          int s0 = scol[e],     s1 = scol[e + 1], s2 = scol[e + 2], s3 = scol[e + 3];
          int s4 = scol[e + 4], s5 = scol[e + 5], s6 = scol[e + 6], s7 = scol[e + 7];
          uint4 u0 = *(const uint4*)(tc + (size_t)s0 * 96);
          uint4 u1 = *(const uint4*)(tc + (size_t)s1 * 96);
          uint4 u2 = *(const uint4*)(tc + (size_t)s2 * 96);
          uint4 u3 = *(const uint4*)(tc + (size_t)s3 * 96);
          uint4 u4 = *(const uint4*)(tc + (size_t)s4 * 96);
          uint4 u5 = *(const uint4*)(tc + (size_t)s5 * 96);
          uint4 u6 = *(const uint4*)(tc + (size_t)s6 * 96);
          uint4 u7 = *(const uint4*)(tc + (size_t)s7 * 96);
          ACC8(u0); ACC8(u1); ACC8(u2); ACC8(u3);
          ACC8(u4); ACC8(u5); ACC8(u6); ACC8(u7);
        }
        for (; e < end; ++e) {
          int s0 = scol[e];
          uint4 u4 = *(const uint4*)(tc + (size_t)s0 * 96);
          ACC8(u4);
        }
      } else {  // ~never: degree mass above CAP
        int e = beg;
        for (; e < end; ++e) {
          int s0 = col[gs + e];
          uint4 u4 = *(const uint4*)(tc + (size_t)s0 * 96);
          ACC8(u4);
        }
      }
      const float* b = bias + 8 * c;
      union { unsigned short s[8]; uint4 u; } pk;
      pk.s[0] = f2bf(fmaxf(a0 + b[0], 0.f));
      pk.s[1] = f2bf(fmaxf(a1 + b[1], 0.f));
      pk.s[2] = f2bf(fmaxf(a2 + b[2], 0.f));
      pk.s[3] = f2bf(fmaxf(a3 + b[3], 0.f));
      pk.s[4] = f2bf(fmaxf(a4 + b[4], 0.f));
      pk.s[5] = f2bf(fmaxf(a5 + b[5], 0.f));
      pk.s[6] = f2bf(fmaxf(a6 + b[6], 0.f));
      pk.s[7] = f2bf(fmaxf(a7 + b[7], 0.f));
      *(uint4*)&sH[nl * LST + c * 8] = pk.u;
    }
  }
  __syncthreads();

  // ---- Phase B: MFMA tile per wave; per-step B-frag reload ----
  int wid = tid >> 6;
  int lane = tid & 63;
  int rt16 = wid * 16;
  if (node0 + rt16 >= N) return;
  int quad = lane >> 4;
  int lm = lane & 15;
  union BU { uint4 u; bf16x8 v; };
  f32x4 acc[NCT];
#pragma unroll
  for (int c = 0; c < NCT; ++c) acc[c] = (f32x4){0.f, 0.f, 0.f, 0.f};
  const uint4* wp4 = (const uint4*)Wp;
#pragma unroll
  for (int s = 0; s < 3; ++s) {
    BU au;
    au.u = *(const uint4*)&sH[(rt16 + lm) * LST + s * 32 + quad * 8];
#pragma unroll
    for (int c = 0; c < NCT; ++c) {
      BU bu;
      bu.u = wp4[(s * NCT + c) * 64 + lane];
      acc[c] = __builtin_amdgcn_mfma_f32_16x16x32_bf16(au.v, bu.v, acc[c], 0, 0, 0);
    }
  }
#pragma unroll
  for (int c = 0; c < NCT; ++c) {
    int colv = c * 16 + lm;
    if (colv >= MVALID) continue;
#pragma unroll
    for (int r = 0; r < 4; ++r) {
      int orow = node0 + rt16 + quad * 4 + r;
      if (orow < N) outp[(size_t)orow * MOUT + colv] = f2bf(acc[c][r]);
    }
  }
}

// Layer-3 aggregation (bf16 in) + bias + log_softmax over 40 classes.
// Block = 32 nodes; 8-lane group per node; lanes 0..4 hold 8 classes each
// (uint4 loads: 5 VMEM/edge vs 10 with uint2). Group shuffle reduction.
__global__ __launch_bounds__(256) void agg_lsm_bf16(const unsigned short* __restrict__ t,
                                                    const int* __restrict__ row_ptr,
                                                    const int* __restrict__ col,
                                                    const float* __restrict__ bias,
                                                    float* __restrict__ out, int N) {
  constexpr int CAPL = 1024;  // staged edges (mean 512, ~22 sigma)
  __shared__ int scol[CAPL];
  __shared__ int srp[33];
  int tid = threadIdx.x;
  int node0 = blockIdx.x * 32;
  int nloc = N - node0;
  if (nloc > 32) nloc = 32;
  if (tid <= nloc) srp[tid] = row_ptr[node0 + tid];
  __syncthreads();
  int gs = srp[0];
  int me = srp[nloc] - gs;
  for (int i = tid; i < me && i < CAPL; i += 256) scol[i] = col[gs + i];
  __syncthreads();
  bool fits = (me <= CAPL);

  int nl = tid >> 3;  // node-in-block 0..31
  int j = tid & 7;    // lane-in-group; 0..4 active
  bool act = (j < 5) && (nl < nloc);
  int jeff = (j < 5) ? j : 0;
  const unsigned short* tc = t + 8 * jeff;
  float a0 = 0.f, a1 = 0.f, a2 = 0.f, a3 = 0.f, a4 = 0.f, a5 = 0.f, a6 = 0.f, a7 = 0.f;
  if (act) {
    int beg = srp[nl] - gs;
    int end = srp[nl + 1] - gs;
    if (fits) {
      int e = beg;
      for (; e + 3 < end; e += 4) {
        int s0 = scol[e], s1 = scol[e + 1], s2 = scol[e + 2], s3 = scol[e + 3];
        uint4 u0 = *(const uint4*)(tc + (size_t)s0 * 40);
        uint4 u1 = *(const uint4*)(tc + (size_t)s1 * 40);
        uint4 u2 = *(const uint4*)(tc + (size_t)s2 * 40);
        uint4 u3 = *(const uint4*)(tc + (size_t)s3 * 40);
        ACC8(u0); ACC8(u1); ACC8(u2); ACC8(u3);
      }
      for (; e < end; ++e) {
        int s0 = scol[e];
        uint4 u4 = *(const uint4*)(tc + (size_t)s0 * 40);
        ACC8(u4);
      }
    } else {
      for (int e = beg; e < end; ++e) {
        int s0 = col[gs + e];
        uint4 u4 = *(const uint4*)(tc + (size_t)s0 * 40);
        ACC8(u4);
      }
    }
  }
  const float* bb = bias + 8 * jeff;
  a0 += bb[0]; a1 += bb[1]; a2 += bb[2]; a3 += bb[3];
  a4 += bb[4]; a5 += bb[5]; a6 += bb[6]; a7 += bb[7];
  float m = act ? fmaxf(fmaxf(fmaxf(a0, a1), fmaxf(a2, a3)),
                        fmaxf(fmaxf(a4, a5), fmaxf(a6, a7)))
                : -__builtin_inff();
  m = fmaxf(m, __shfl_down(m, 4, 8));
  m = fmaxf(m, __shfl_down(m, 2, 8));
  m = fmaxf(m, __shfl_down(m, 1, 8));
  m = __shfl(m, 0, 8);  // broadcast group max
  float ex = act ? (__expf(a0 - m) + __expf(a1 - m) + __expf(a2 - m) + __expf(a3 - m) +
                    __expf(a4 - m) + __expf(a5 - m) + __expf(a6 - m) + __expf(a7 - m))
                 : 0.f;
  ex += __shfl_down(ex, 4, 8);
  ex += __shfl_down(ex, 2, 8);
  ex += __shfl_down(ex, 1, 8);
  ex = __shfl(ex, 0, 8);
  if (act) {
    int node = node0 + nl;
    float l = m + __logf(ex);
    float* o = out + (size_t)node * 40 + 8 * j;
    o[0] = a0 - l; o[1] = a1 - l; o[2] = a2 - l; o[3] = a3 - l;
    o[4] = a4 - l; o[5] = a5 - l; o[6] = a6 - l; o[7] = a7 - l;
  }
}

// ================= Launch =================

extern "C" void kernel_launch(void* const* d_in, const int* in_sizes, int n_in,
                              void* d_out, int out_size, void* d_ws, size_t ws_size,
                              hipStream_t stream) {
  const float* x  = (const float*)d_in[0];
  const float* W1 = (const float*)d_in[1];
  const float* b1 = (const float*)d_in[2];
  const float* W2 = (const float*)d_in[3];
  const float* b2 = (const float*)d_in[4];
  const float* W3 = (const float*)d_in[5];
  const float* b3 = (const float*)d_in[6];
  const int* edge = (const int*)d_in[7];

  int N = in_sizes[0] / 128;  // 50000
  int E = in_sizes[7] / 2;    // 800000
  const int* srcp = edge;
  const int* dstp = edge + E;

  char* p = (char*)d_ws;
  auto alloc = [&](size_t bytes) {
    char* r = p;
    p += (bytes + 255) & ~size_t(255);
    return r;
  };
  int NB = (N + 127) >> 7;  // 391 buckets of 128 nodes
  int* partial = (int*)alloc((size_t)CB * 512 * 4);
  int* gstart  = (int*)alloc((size_t)(NB + 1) * 4);
  int* gcur    = (int*)alloc((size_t)NB * 4);
  int* row_ptr = (int*)alloc((size_t)(N + 1) * 4);
  int* packed  = (int*)alloc((size_t)E * 4);
  int* col     = (int*)alloc((size_t)E * 4);
  unsigned short* Wp1 = (unsigned short*)alloc(1536 * 8 * 2);
  unsigned short* Wp2 = (unsigned short*)alloc(1152 * 8 * 2);
  unsigned short* Wp3 = (unsigned short*)alloc(576 * 8 * 2);
  unsigned short* Tb  = (unsigned short*)alloc((size_t)N * 96 * 2);   // t1
  unsigned short* T2b = (unsigned short*)alloc((size_t)N * 96 * 2);   // t2
  unsigned short* T3b = (unsigned short*)alloc((size_t)N * 40 * 2);   // t3

  int NBIN = (E + EB - 1) / EB;      // 196 binning blocks
  int GB = ((N + 15) / 16 + 3) / 4;  // gemm1 blocks (4 row-tiles each)
  int FB = (N + 63) / 64;            // fused blocks (64 nodes each)

  // 1: bucket count + W1/W2/W3 pack
  count_pack<<<CB + 13, 256, 0, stream>>>(dstp, partial, E, W1, W2, W3, Wp1, Wp2, Wp3);
  // 2: scan bucket totals
  scan_kernel<<<1, 256, 0, stream>>>(partial, gstart, gcur, row_ptr, NB, N, E);
  // 3: LDS-staged bin + gemm1 (independent halves, overlap)
  bin_gemm1<<<NBIN + GB, 256, 0, stream>>>(srcp, dstp, gcur, packed, E, NB, NBIN,
                                           x, Wp1, Tb, N);
  // 4: per-bucket CSR finalize
  build_local_csr<<<NB, 256, 0, stream>>>(packed, gstart, row_ptr, col, N);
  // 5: t2 = relu(agg(t1)+b1) @ W2
  fused_agg_gemm<6, 96, 96><<<FB, 256, 0, stream>>>(Tb, row_ptr, col, b1, Wp2, T2b, N);
  // 6: t3 = relu(agg(t2)+b2) @ W3
  fused_agg_gemm<3, 40, 40><<<FB, 256, 0, stream>>>(T2b, row_ptr, col, b2, Wp3, T3b, N);
  // 7: out = log_softmax(agg(t3) + b3)
  agg_lsm_bf16<<<(N + 31) / 32, 256, 0, stream>>>(T3b, row_ptr, col, b3, (float*)d_out, N);
}

// Round 11
// 193.410 us; speedup vs baseline: 1.0874x; 1.0874x over previous
//
#include <hip/hip_runtime.h>
#include <math.h>

typedef __attribute__((ext_vector_type(8))) short bf16x8;
typedef __attribute__((ext_vector_type(4))) float f32x4;

__device__ __forceinline__ unsigned short f2bf(float f) {
  unsigned u = __float_as_uint(f);
  u += 0x7fffu + ((u >> 16) & 1u);  // round-to-nearest-even
  return (unsigned short)(u >> 16);
}
__device__ __forceinline__ float bflo(unsigned u) { return __uint_as_float(u << 16); }
__device__ __forceinline__ float bfhi(unsigned u) { return __uint_as_float(u & 0xffff0000u); }

#define ACC8(U)                                           \
  a0 += bflo(U.x); a1 += bfhi(U.x); a2 += bflo(U.y); a3 += bfhi(U.y); \
  a4 += bflo(U.z); a5 += bfhi(U.z); a6 += bflo(U.w); a7 += bfhi(U.w)

// ================= CSR via two-level bucket binning =================
// Buckets of 128 nodes (NB = ceil(N/128) = 391 <= 512). packed edge =
// (d_local<<16)|src. Requires N <= 65536 — N = 50000 here.

constexpr int CB = 64;    // histogram blocks
constexpr int EB = 4096;  // edges per binning block

__global__ __launch_bounds__(256) void count_pack(const int* __restrict__ dst,
                                                  int* __restrict__ partial, int E,
                                                  const float* __restrict__ W1,
                                                  const float* __restrict__ W2,
                                                  const float* __restrict__ W3,
                                                  unsigned short* __restrict__ Wp1,
                                                  unsigned short* __restrict__ Wp2,
                                                  unsigned short* __restrict__ Wp3) {
  int tid = threadIdx.x;
  if (blockIdx.x < CB) {
    __shared__ int bkt[512];
    bkt[tid] = 0;
    bkt[tid + 256] = 0;
    __syncthreads();
    int E4 = E >> 2;
    const int4* d4 = (const int4*)dst;
    for (int i = blockIdx.x * 256 + tid; i < E4; i += CB * 256) {
      int4 d = d4[i];
      atomicAdd(&bkt[d.x >> 7], 1);
      atomicAdd(&bkt[d.y >> 7], 1);
      atomicAdd(&bkt[d.z >> 7], 1);
      atomicAdd(&bkt[d.w >> 7], 1);
    }
    if (blockIdx.x == 0 && tid < (E & 3)) atomicAdd(&bkt[dst[E4 * 4 + tid] >> 7], 1);
    __syncthreads();
    partial[blockIdx.x * 512 + tid] = bkt[tid];
    partial[blockIdx.x * 512 + tid + 256] = bkt[tid + 256];
    return;
  }
  int gid = (blockIdx.x - CB) * 256 + tid;
  const float* W;
  unsigned short* Wp;
  int t, NCTT, M, MV;
  if (gid < 1536) {            // W1: 4 ksteps * 6 coltiles * 64 lanes
    W = W1; Wp = Wp1; t = gid; NCTT = 6; M = 96; MV = 96;
  } else if (gid < 2688) {     // W2: 3 * 6 * 64
    W = W2; Wp = Wp2; t = gid - 1536; NCTT = 6; M = 96; MV = 96;
  } else if (gid < 3264) {     // W3: 3 * 3 * 64 (cols >= 40 zero-padded)
    W = W3; Wp = Wp3; t = gid - 2688; NCTT = 3; M = 40; MV = 40;
  } else {
    return;
  }
  int lane = t & 63;
  int frag = t >> 6;
  int s = frag / NCTT;
  int ct = frag - s * NCTT;
  int colv = ct * 16 + (lane & 15);
  int k0 = s * 32 + (lane >> 4) * 8;
  union { unsigned short s[8]; uint4 u; } pk;
#pragma unroll
  for (int j = 0; j < 8; ++j) {
    float v = (colv < MV) ? W[(k0 + j) * M + colv] : 0.f;
    pk.s[j] = f2bf(v);
  }
  ((uint4*)Wp)[t] = pk.u;
}

__global__ __launch_bounds__(256) void scan_kernel(const int* __restrict__ partial,
                                                   int* __restrict__ gstart,
                                                   int* __restrict__ gcur,
                                                   int* __restrict__ row_ptr,
                                                   int NB, int N, int E) {
  __shared__ int sm[512];
  int tid = threadIdx.x;
  int s0 = 0, s1 = 0;
#pragma unroll 8
  for (int i = 0; i < CB; ++i) {
    s0 += partial[i * 512 + tid];
    s1 += partial[i * 512 + tid + 256];
  }
  sm[tid] = s0;
  sm[tid + 256] = s1;
  __syncthreads();
  for (int off = 1; off < 512; off <<= 1) {
    int a0 = (tid >= off) ? sm[tid - off] : 0;
    int i1 = tid + 256;
    int a1 = (i1 >= off) ? sm[i1 - off] : 0;
    __syncthreads();
    sm[tid] += a0;
    sm[i1] += a1;
    __syncthreads();
  }
  int e0 = sm[tid] - s0;
  int e1 = sm[tid + 256] - s1;
  if (tid < NB) { gstart[tid] = e0; gcur[tid] = e0; }
  int b1 = tid + 256;
  if (b1 < NB) { gstart[b1] = e1; gcur[b1] = e1; }
  if (tid == 255) gstart[NB] = sm[511];
  if (tid == 0) row_ptr[N] = E;
}

// gemm1 row-tile worker: block bx covers rows [bx*64, bx*64+64).
__device__ __forceinline__ void gemm1_tile(int bx, int tid, const float* __restrict__ x,
                                           const unsigned short* __restrict__ Wp1,
                                           unsigned short* __restrict__ Tb, int N) {
  int wid = tid >> 6;
  int lane = tid & 63;
  int rt = bx * 4 + wid;
  if (rt * 16 >= N) return;
  int quad = lane >> 4;
  int lm = lane & 15;
  union BU { uint4 u; bf16x8 v; };
  f32x4 acc[6];
#pragma unroll
  for (int c = 0; c < 6; ++c) acc[c] = (f32x4){0.f, 0.f, 0.f, 0.f};
  int row = rt * 16 + lm;
  if (row >= N) row = N - 1;  // safe dup read; epilogue guards rows
  const uint4* wp4 = (const uint4*)Wp1;
#pragma unroll
  for (int s = 0; s < 4; ++s) {
    int k0 = s * 32 + quad * 8;
    const float* Af = x + (size_t)row * 128 + k0;
    float4 x0 = *(const float4*)(Af);
    float4 x1 = *(const float4*)(Af + 4);
    union { unsigned short s[8]; bf16x8 v; } au;
    au.s[0] = f2bf(x0.x); au.s[1] = f2bf(x0.y); au.s[2] = f2bf(x0.z); au.s[3] = f2bf(x0.w);
    au.s[4] = f2bf(x1.x); au.s[5] = f2bf(x1.y); au.s[6] = f2bf(x1.z); au.s[7] = f2bf(x1.w);
#pragma unroll
    for (int c = 0; c < 6; ++c) {
      BU bu;
      bu.u = wp4[(s * 6 + c) * 64 + lane];
      acc[c] = __builtin_amdgcn_mfma_f32_16x16x32_bf16(au.v, bu.v, acc[c], 0, 0, 0);
    }
  }
#pragma unroll
  for (int c = 0; c < 6; ++c) {
    int colv = c * 16 + lm;
#pragma unroll
    for (int r = 0; r < 4; ++r) {
      int orow = rt * 16 + quad * 4 + r;
      if (orow < N) Tb[(size_t)orow * 96 + colv] = f2bf(acc[c][r]);
    }
  }
}

// Dispatch 3: [0,NBIN) LDS-staged binning; [NBIN,NBIN+GB1) first half of gemm1.
__global__ __launch_bounds__(256) void bin_gemm1(const int* __restrict__ src,
                                                 const int* __restrict__ dst,
                                                 int* __restrict__ gcur,
                                                 int* __restrict__ packed, int E, int NB,
                                                 int NBIN, const float* __restrict__ x,
                                                 const unsigned short* __restrict__ Wp1,
                                                 unsigned short* __restrict__ Tb, int N) {
  __shared__ int lcnt[512];
  __shared__ int lstart[512];
  __shared__ int gbase[512];
  __shared__ int cur[512];
  __shared__ int stage[EB];
  int tid = threadIdx.x;
  if (blockIdx.x < NBIN) {
    lcnt[tid] = 0;
    lcnt[tid + 256] = 0;
    __syncthreads();
    int E4 = E >> 2;
    int base4 = blockIdx.x * (EB >> 2);
    int sv[16], dv[16];
    int nv = 0;
#pragma unroll
    for (int j = 0; j < 4; ++j) {
      int idx4 = base4 + j * 256 + tid;
      if (idx4 < E4 && idx4 < base4 + (EB >> 2)) {
        int4 s4 = ((const int4*)src)[idx4];
        int4 d4 = ((const int4*)dst)[idx4];
        sv[j * 4 + 0] = s4.x; dv[j * 4 + 0] = d4.x;
        sv[j * 4 + 1] = s4.y; dv[j * 4 + 1] = d4.y;
        sv[j * 4 + 2] = s4.z; dv[j * 4 + 2] = d4.z;
        sv[j * 4 + 3] = s4.w; dv[j * 4 + 3] = d4.w;
        nv = j * 4 + 4;
      }
    }
#pragma unroll
    for (int i = 0; i < 16; ++i)
      if (i < nv) atomicAdd(&lcnt[dv[i] >> 7], 1);
    bool last = (blockIdx.x == NBIN - 1);
    int tl = E & 3;
    if (last && tid == 0)
      for (int t = 0; t < tl; ++t) atomicAdd(&lcnt[dst[E4 * 4 + t] >> 7], 1);
    __syncthreads();
    lstart[tid] = lcnt[tid];
    lstart[tid + 256] = lcnt[tid + 256];
    __syncthreads();
    for (int off = 1; off < 512; off <<= 1) {
      int a0 = (tid >= off) ? lstart[tid - off] : 0;
      int i1 = tid + 256;
      int a1 = (i1 >= off) ? lstart[i1 - off] : 0;
      __syncthreads();
      lstart[tid] += a0;
      lstart[i1] += a1;
      __syncthreads();
    }
    int e0 = lstart[tid] - lcnt[tid];
    int e1 = lstart[tid + 256] - lcnt[tid + 256];
    __syncthreads();
    lstart[tid] = e0; cur[tid] = e0;
    lstart[tid + 256] = e1; cur[tid + 256] = e1;
    __syncthreads();
#pragma unroll
    for (int i = 0; i < 16; ++i)
      if (i < nv) {
        int b = dv[i] >> 7;
        int p = atomicAdd(&cur[b], 1);
        stage[p] = ((dv[i] & 127) << 16) | (sv[i] & 0xffff);
      }
    if (last && tid == 0)
      for (int t = 0; t < tl; ++t) {
        int d = dst[E4 * 4 + t], s = src[E4 * 4 + t];
        int p = atomicAdd(&cur[d >> 7], 1);
        stage[p] = ((d & 127) << 16) | (s & 0xffff);
      }
    if (lcnt[tid]) gbase[tid] = atomicAdd(&gcur[tid], lcnt[tid]);
    if (lcnt[tid + 256]) gbase[tid + 256] = atomicAdd(&gcur[tid + 256], lcnt[tid + 256]);
    __syncthreads();
    int meB = lstart[511] + lcnt[511];
    for (int i = tid; i < meB; i += 256) {
      int lo = 0, hi = 511;
      while (lo < hi) {
        int mid = (lo + hi + 1) >> 1;
        if (lstart[mid] <= i) lo = mid; else hi = mid - 1;
      }
      packed[gbase[lo] + (i - lstart[lo])] = stage[i];
    }
    return;
  }
  gemm1_tile(blockIdx.x - NBIN, tid, x, Wp1, Tb, N);
}

// Dispatch 4: [0,NB) per-bucket CSR finalize; [NB,NB+GB2) second half of gemm1.
__global__ __launch_bounds__(256) void build_gemm1(const int* __restrict__ packed,
                                                   const int* __restrict__ gstart,
                                                   int* __restrict__ row_ptr,
                                                   int* __restrict__ col, int N, int NB,
                                                   int GB1, const float* __restrict__ x,
                                                   const unsigned short* __restrict__ Wp1,
                                                   unsigned short* __restrict__ Tb) {
  int tid = threadIdx.x;
  if (blockIdx.x >= (unsigned)NB) {
    gemm1_tile(blockIdx.x - NB + GB1, tid, x, Wp1, Tb, N);
    return;
  }
  __shared__ int cnt[128];
  __shared__ int sm[128];
  int b = blockIdx.x;
  int gs = gstart[b], ge = gstart[b + 1];
  int me = ge - gs;
  int node0 = b << 7;
  int RL = N - node0;
  if (RL > 128) RL = 128;
  if (tid < 128) cnt[tid] = 0;
  __syncthreads();
  for (int i = tid; i < me; i += 256) atomicAdd(&cnt[packed[gs + i] >> 16], 1);
  __syncthreads();
  if (tid < 128) sm[tid] = cnt[tid];
  __syncthreads();
  for (int off = 1; off < 128; off <<= 1) {
    int u = (tid >= off && tid < 128) ? sm[tid - off] : 0;
    __syncthreads();
    if (tid < 128) sm[tid] += u;
    __syncthreads();
  }
  if (tid < 128) {
    int excl = gs + sm[tid] - cnt[tid];
    cnt[tid] = excl;
    if (tid < RL) row_ptr[node0 + tid] = excl;
  }
  __syncthreads();
  for (int i = tid; i < me; i += 256) {
    int pk = packed[gs + i];
    int p = atomicAdd(&cnt[pk >> 16], 1);
    col[p] = pk & 0xffff;
  }
}

// ================= Fused aggregation + GEMM =================
// Block owns 64 nodes; col + row_ptr staged in LDS. Phase A: unroll x4
// (R10 post-mortem: x8 exceeded the VGPR cap and regressed -14us), fits-flag
// hoisted so the hot loop is branchless LDS-index only. Phase B: 4 waves x
// 16-row MFMA tiles; per-step B reload (VGPR <= 73 for 7 blocks/CU).

template <int NCT, int MOUT, int MVALID>
__global__ __launch_bounds__(256, 7) void fused_agg_gemm(
    const unsigned short* __restrict__ tin, const int* __restrict__ row_ptr,
    const int* __restrict__ col, const float* __restrict__ bias,
    const unsigned short* __restrict__ Wp, unsigned short* __restrict__ outp, int N) {
  constexpr int LST = 104;   // bf16 units per LDS row
  constexpr int CAP = 1536;  // staged edges (mean 1024, ~16 sigma)
  __shared__ unsigned short sH[64 * LST];
  __shared__ int scol[CAP];
  __shared__ int srp[65];
  int tid = threadIdx.x;
  int node0 = blockIdx.x * 64;
  int nloc = N - node0;
  if (nloc > 64) nloc = 64;
  if (tid <= nloc) srp[tid] = row_ptr[node0 + tid];
  __syncthreads();
  int gs = srp[0];
  int me = srp[nloc] - gs;
  for (int i = tid; i < me && i < CAP; i += 256) scol[i] = col[gs + i];
  __syncthreads();
  bool fits = (me <= CAP);

  // ---- Phase A: aggregate 64 nodes x 12 chunks of 8 bf16, unroll x4 ----
#pragma unroll
  for (int it = 0; it < 3; ++it) {
    int u = tid + it * 256;
    int nl = u / 12;
    int c = u - nl * 12;
    if (nl < nloc) {
      int beg = srp[nl] - gs;
      int end = srp[nl + 1] - gs;
      const unsigned short* tc = tin + 8 * c;
      float a0 = 0.f, a1 = 0.f, a2 = 0.f, a3 = 0.f, a4 = 0.f, a5 = 0.f, a6 = 0.f, a7 = 0.f;
      if (fits) {
        int e = beg;
        for (; e + 3 < end; e += 4) {
          int s0 = scol[e], s1 = scol[e + 1], s2 = scol[e + 2], s3 = scol[e + 3];
          uint4 u0 = *(const uint4*)(tc + (size_t)s0 * 96);
          uint4 u1 = *(const uint4*)(tc + (size_t)s1 * 96);
          uint4 u2 = *(const uint4*)(tc + (size_t)s2 * 96);
          uint4 u3 = *(const uint4*)(tc + (size_t)s3 * 96);
          ACC8(u0); ACC8(u1); ACC8(u2); ACC8(u3);
        }
        for (; e < end; ++e) {
          int s0 = scol[e];
          uint4 u4 = *(const uint4*)(tc + (size_t)s0 * 96);
          ACC8(u4);
        }
      } else {  // ~never: degree mass above CAP
        for (int e = beg; e < end; ++e) {
          int s0 = col[gs + e];
          uint4 u4 = *(const uint4*)(tc + (size_t)s0 * 96);
          ACC8(u4);
        }
      }
      const float* b = bias + 8 * c;
      union { unsigned short s[8]; uint4 u; } pk;
      pk.s[0] = f2bf(fmaxf(a0 + b[0], 0.f));
      pk.s[1] = f2bf(fmaxf(a1 + b[1], 0.f));
      pk.s[2] = f2bf(fmaxf(a2 + b[2], 0.f));
      pk.s[3] = f2bf(fmaxf(a3 + b[3], 0.f));
      pk.s[4] = f2bf(fmaxf(a4 + b[4], 0.f));
      pk.s[5] = f2bf(fmaxf(a5 + b[5], 0.f));
      pk.s[6] = f2bf(fmaxf(a6 + b[6], 0.f));
      pk.s[7] = f2bf(fmaxf(a7 + b[7], 0.f));
      *(uint4*)&sH[nl * LST + c * 8] = pk.u;
    }
  }
  __syncthreads();

  // ---- Phase B: MFMA tile per wave; per-step B-frag reload ----
  int wid = tid >> 6;
  int lane = tid & 63;
  int rt16 = wid * 16;
  if (node0 + rt16 >= N) return;
  int quad = lane >> 4;
  int lm = lane & 15;
  union BU { uint4 u; bf16x8 v; };
  f32x4 acc[NCT];
#pragma unroll
  for (int c = 0; c < NCT; ++c) acc[c] = (f32x4){0.f, 0.f, 0.f, 0.f};
  const uint4* wp4 = (const uint4*)Wp;
#pragma unroll
  for (int s = 0; s < 3; ++s) {
    BU au;
    au.u = *(const uint4*)&sH[(rt16 + lm) * LST + s * 32 + quad * 8];
#pragma unroll
    for (int c = 0; c < NCT; ++c) {
      BU bu;
      bu.u = wp4[(s * NCT + c) * 64 + lane];
      acc[c] = __builtin_amdgcn_mfma_f32_16x16x32_bf16(au.v, bu.v, acc[c], 0, 0, 0);
    }
  }
#pragma unroll
  for (int c = 0; c < NCT; ++c) {
    int colv = c * 16 + lm;
    if (colv >= MVALID) continue;
#pragma unroll
    for (int r = 0; r < 4; ++r) {
      int orow = node0 + rt16 + quad * 4 + r;
      if (orow < N) outp[(size_t)orow * MOUT + colv] = f2bf(acc[c][r]);
    }
  }
}

// Layer-3 aggregation (bf16 in) + bias + log_softmax, col staged in LDS.
// Block = 16 nodes; 16-lane group per node (R10 post-mortem: 8-lane groups
// doubled per-wave degree divergence and regressed); lanes 0..9 hold 4
// classes each (uint2).

__global__ __launch_bounds__(256) void agg_lsm_bf16(const unsigned short* __restrict__ t,
                                                    const int* __restrict__ row_ptr,
                                                    const int* __restrict__ col,
                                                    const float* __restrict__ bias,
                                                    float* __restrict__ out, int N) {
  constexpr int CAPL = 1024;  // staged edges (mean 256)
  __shared__ int scol[CAPL];
  __shared__ int srp[17];
  int tid = threadIdx.x;
  int node0 = blockIdx.x * 16;
  int nloc = N - node0;
  if (nloc > 16) nloc = 16;
  if (tid <= nloc) srp[tid] = row_ptr[node0 + tid];
  __syncthreads();
  int gs = srp[0];
  int me = srp[nloc] - gs;
  for (int i = tid; i < me && i < CAPL; i += 256) scol[i] = col[gs + i];
  __syncthreads();
  bool fits = (me <= CAPL);

  int nl = tid >> 4;
  int c = tid & 15;  // 0..9 active
  bool act = (c < 10) && (nl < nloc);
  int ceff = (c < 10) ? c : 0;
  const unsigned short* tc = t + 4 * ceff;
  float v0 = 0.f, v1 = 0.f, v2 = 0.f, v3 = 0.f;
  if (act) {
    int beg = srp[nl] - gs;
    int end = srp[nl + 1] - gs;
    if (fits) {
      int e = beg;
      for (; e + 3 < end; e += 4) {
        int s0 = scol[e], s1 = scol[e + 1], s2 = scol[e + 2], s3 = scol[e + 3];
        uint2 u = *(const uint2*)(tc + (size_t)s0 * 40);
        uint2 w = *(const uint2*)(tc + (size_t)s1 * 40);
        uint2 y = *(const uint2*)(tc + (size_t)s2 * 40);
        uint2 z = *(const uint2*)(tc + (size_t)s3 * 40);
        v0 += bflo(u.x); v1 += bfhi(u.x); v2 += bflo(u.y); v3 += bfhi(u.y);
        v0 += bflo(w.x); v1 += bfhi(w.x); v2 += bflo(w.y); v3 += bfhi(w.y);
        v0 += bflo(y.x); v1 += bfhi(y.x); v2 += bflo(y.y); v3 += bfhi(y.y);
        v0 += bflo(z.x); v1 += bfhi(z.x); v2 += bflo(z.y); v3 += bfhi(z.y);
      }
      for (; e < end; ++e) {
        int s0 = scol[e];
        uint2 u = *(const uint2*)(tc + (size_t)s0 * 40);
        v0 += bflo(u.x); v1 += bfhi(u.x); v2 += bflo(u.y); v3 += bfhi(u.y);
      }
    } else {
      for (int e = beg; e < end; ++e) {
        int s0 = col[gs + e];
        uint2 u = *(const uint2*)(tc + (size_t)s0 * 40);
        v0 += bflo(u.x); v1 += bfhi(u.x); v2 += bflo(u.y); v3 += bfhi(u.y);
      }
    }
  }
  const float* bb = bias + 4 * ceff;
  v0 += bb[0]; v1 += bb[1]; v2 += bb[2]; v3 += bb[3];
  float m = act ? fmaxf(fmaxf(v0, v1), fmaxf(v2, v3)) : -__builtin_inff();
#pragma unroll
  for (int off = 8; off; off >>= 1) m = fmaxf(m, __shfl_xor(m, off, 64));
  float ex = act ? (__expf(v0 - m) + __expf(v1 - m) + __expf(v2 - m) + __expf(v3 - m)) : 0.f;
#pragma unroll
  for (int off = 8; off; off >>= 1) ex += __shfl_xor(ex, off, 64);
  if (act) {
    int node = node0 + nl;
    float l = m + __logf(ex);
    float* o = out + (size_t)node * 40 + 4 * c;
    o[0] = v0 - l; o[1] = v1 - l; o[2] = v2 - l; o[3] = v3 - l;
  }
}

// ================= Launch =================

extern "C" void kernel_launch(void* const* d_in, const int* in_sizes, int n_in,
                              void* d_out, int out_size, void* d_ws, size_t ws_size,
                              hipStream_t stream) {
  const float* x  = (const float*)d_in[0];
  const float* W1 = (const float*)d_in[1];
  const float* b1 = (const float*)d_in[2];
  const float* W2 = (const float*)d_in[3];
  const float* b2 = (const float*)d_in[4];
  const float* W3 = (const float*)d_in[5];
  const float* b3 = (const float*)d_in[6];
  const int* edge = (const int*)d_in[7];

  int N = in_sizes[0] / 128;  // 50000
  int E = in_sizes[7] / 2;    // 800000
  const int* srcp = edge;
  const int* dstp = edge + E;

  char* p = (char*)d_ws;
  auto alloc = [&](size_t bytes) {
    char* r = p;
    p += (bytes + 255) & ~size_t(255);
    return r;
  };
  int NB = (N + 127) >> 7;  // 391 buckets of 128 nodes
  int* partial = (int*)alloc((size_t)CB * 512 * 4);
  int* gstart  = (int*)alloc((size_t)(NB + 1) * 4);
  int* gcur    = (int*)alloc((size_t)NB * 4);
  int* row_ptr = (int*)alloc((size_t)(N + 1) * 4);
  int* packed  = (int*)alloc((size_t)E * 4);
  int* col     = (int*)alloc((size_t)E * 4);
  unsigned short* Wp1 = (unsigned short*)alloc(1536 * 8 * 2);
  unsigned short* Wp2 = (unsigned short*)alloc(1152 * 8 * 2);
  unsigned short* Wp3 = (unsigned short*)alloc(576 * 8 * 2);
  unsigned short* Tb  = (unsigned short*)alloc((size_t)N * 96 * 2);   // t1
  unsigned short* T2b = (unsigned short*)alloc((size_t)N * 96 * 2);   // t2
  unsigned short* T3b = (unsigned short*)alloc((size_t)N * 40 * 2);   // t3

  int NBIN = (E + EB - 1) / EB;      // 196 binning blocks
  int GB = ((N + 15) / 16 + 3) / 4;  // 782 gemm1 blocks (4 row-tiles each)
  int GB1 = GB / 2;                  // first half with bin (d3)
  int GB2 = GB - GB1;                // second half with build (d4)
  int FB = (N + 63) / 64;            // fused blocks (64 nodes each)

  // 1: bucket count + W1/W2/W3 pack
  count_pack<<<CB + 13, 256, 0, stream>>>(dstp, partial, E, W1, W2, W3, Wp1, Wp2, Wp3);
  // 2: scan bucket totals
  scan_kernel<<<1, 256, 0, stream>>>(partial, gstart, gcur, row_ptr, NB, N, E);
  // 3: LDS-staged bin + gemm1 rows [0, GB1*64)
  bin_gemm1<<<NBIN + GB1, 256, 0, stream>>>(srcp, dstp, gcur, packed, E, NB, NBIN,
                                            x, Wp1, Tb, N);
  // 4: per-bucket CSR finalize + gemm1 rows [GB1*64, N)
  build_gemm1<<<NB + GB2, 256, 0, stream>>>(packed, gstart, row_ptr, col, N, NB,
                                            GB1, x, Wp1, Tb);
  // 5: t2 = relu(agg(t1)+b1) @ W2
  fused_agg_gemm<6, 96, 96><<<FB, 256, 0, stream>>>(Tb, row_ptr, col, b1, Wp2, T2b, N);
  // 6: t3 = relu(agg(t2)+b2) @ W3
  fused_agg_gemm<3, 40, 40><<<FB, 256, 0, stream>>>(T2b, row_ptr, col, b2, Wp3, T3b, N);
  // 7: out = log_softmax(agg(t3) + b3)
  agg_lsm_bf16<<<(N + 15) / 16, 256, 0, stream>>>(T3b, row_ptr, col, b3, (float*)d_out, N);
}

// Round 12
// 192.083 us; speedup vs baseline: 1.0949x; 1.0069x over previous
//
#include <hip/hip_runtime.h>
#include <math.h>

typedef __attribute__((ext_vector_type(8))) short bf16x8;
typedef __attribute__((ext_vector_type(4))) float f32x4;

__device__ __forceinline__ unsigned short f2bf(float f) {
  unsigned u = __float_as_uint(f);
  u += 0x7fffu + ((u >> 16) & 1u);  // round-to-nearest-even
  return (unsigned short)(u >> 16);
}
__device__ __forceinline__ float bflo(unsigned u) { return __uint_as_float(u << 16); }
__device__ __forceinline__ float bfhi(unsigned u) { return __uint_as_float(u & 0xffff0000u); }

#define ACC8(U)                                           \
  a0 += bflo(U.x); a1 += bfhi(U.x); a2 += bflo(U.y); a3 += bfhi(U.y); \
  a4 += bflo(U.z); a5 += bfhi(U.z); a6 += bflo(U.w); a7 += bfhi(U.w)

// ================= CSR via two-level bucket binning =================
// Buckets of 128 nodes (NB = ceil(N/128) = 391 <= 512). packed edge =
// (d_local<<16)|src. Requires N <= 65536 — N = 50000 here.

constexpr int CB = 64;    // histogram blocks
constexpr int EB = 4096;  // edges per binning block

__global__ __launch_bounds__(256) void count_pack(const int* __restrict__ dst,
                                                  int* __restrict__ partial, int E,
                                                  const float* __restrict__ W1,
                                                  const float* __restrict__ W2,
                                                  const float* __restrict__ W3,
                                                  unsigned short* __restrict__ Wp1,
                                                  unsigned short* __restrict__ Wp2,
                                                  unsigned short* __restrict__ Wp3) {
  int tid = threadIdx.x;
  if (blockIdx.x < CB) {
    __shared__ int bkt[512];
    bkt[tid] = 0;
    bkt[tid + 256] = 0;
    __syncthreads();
    int E4 = E >> 2;
    const int4* d4 = (const int4*)dst;
    for (int i = blockIdx.x * 256 + tid; i < E4; i += CB * 256) {
      int4 d = d4[i];
      atomicAdd(&bkt[d.x >> 7], 1);
      atomicAdd(&bkt[d.y >> 7], 1);
      atomicAdd(&bkt[d.z >> 7], 1);
      atomicAdd(&bkt[d.w >> 7], 1);
    }
    if (blockIdx.x == 0 && tid < (E & 3)) atomicAdd(&bkt[dst[E4 * 4 + tid] >> 7], 1);
    __syncthreads();
    partial[blockIdx.x * 512 + tid] = bkt[tid];
    partial[blockIdx.x * 512 + tid + 256] = bkt[tid + 256];
    return;
  }
  int gid = (blockIdx.x - CB) * 256 + tid;
  const float* W;
  unsigned short* Wp;
  int t, NCTT, M, MV;
  if (gid < 1536) {            // W1: 4 ksteps * 6 coltiles * 64 lanes
    W = W1; Wp = Wp1; t = gid; NCTT = 6; M = 96; MV = 96;
  } else if (gid < 2688) {     // W2: 3 * 6 * 64
    W = W2; Wp = Wp2; t = gid - 1536; NCTT = 6; M = 96; MV = 96;
  } else if (gid < 3264) {     // W3: 3 * 3 * 64 (cols >= 40 zero-padded)
    W = W3; Wp = Wp3; t = gid - 2688; NCTT = 3; M = 40; MV = 40;
  } else {
    return;
  }
  int lane = t & 63;
  int frag = t >> 6;
  int s = frag / NCTT;
  int ct = frag - s * NCTT;
  int colv = ct * 16 + (lane & 15);
  int k0 = s * 32 + (lane >> 4) * 8;
  union { unsigned short s[8]; uint4 u; } pk;
#pragma unroll
  for (int j = 0; j < 8; ++j) {
    float v = (colv < MV) ? W[(k0 + j) * M + colv] : 0.f;
    pk.s[j] = f2bf(v);
  }
  ((uint4*)Wp)[t] = pk.u;
}

__global__ __launch_bounds__(256) void scan_kernel(const int* __restrict__ partial,
                                                   int* __restrict__ gstart,
                                                   int* __restrict__ gcur,
                                                   int* __restrict__ row_ptr,
                                                   int NB, int N, int E) {
  __shared__ int sm[512];
  int tid = threadIdx.x;
  int s0 = 0, s1 = 0;
#pragma unroll 8
  for (int i = 0; i < CB; ++i) {
    s0 += partial[i * 512 + tid];
    s1 += partial[i * 512 + tid + 256];
  }
  sm[tid] = s0;
  sm[tid + 256] = s1;
  __syncthreads();
  for (int off = 1; off < 512; off <<= 1) {
    int a0 = (tid >= off) ? sm[tid - off] : 0;
    int i1 = tid + 256;
    int a1 = (i1 >= off) ? sm[i1 - off] : 0;
    __syncthreads();
    sm[tid] += a0;
    sm[i1] += a1;
    __syncthreads();
  }
  int e0 = sm[tid] - s0;
  int e1 = sm[tid + 256] - s1;
  if (tid < NB) { gstart[tid] = e0; gcur[tid] = e0; }
  int b1 = tid + 256;
  if (b1 < NB) { gstart[b1] = e1; gcur[b1] = e1; }
  if (tid == 255) gstart[NB] = sm[511];
  if (tid == 0) row_ptr[N] = E;
}

// gemm1 row-tile worker: block bx covers rows [bx*64, bx*64+64).
__device__ __forceinline__ void gemm1_tile(int bx, int tid, const float* __restrict__ x,
                                           const unsigned short* __restrict__ Wp1,
                                           unsigned short* __restrict__ Tb, int N) {
  int wid = tid >> 6;
  int lane = tid & 63;
  int rt = bx * 4 + wid;
  if (rt * 16 >= N) return;
  int quad = lane >> 4;
  int lm = lane & 15;
  union BU { uint4 u; bf16x8 v; };
  f32x4 acc[6];
#pragma unroll
  for (int c = 0; c < 6; ++c) acc[c] = (f32x4){0.f, 0.f, 0.f, 0.f};
  int row = rt * 16 + lm;
  if (row >= N) row = N - 1;  // safe dup read; epilogue guards rows
  const uint4* wp4 = (const uint4*)Wp1;
#pragma unroll
  for (int s = 0; s < 4; ++s) {
    int k0 = s * 32 + quad * 8;
    const float* Af = x + (size_t)row * 128 + k0;
    float4 x0 = *(const float4*)(Af);
    float4 x1 = *(const float4*)(Af + 4);
    union { unsigned short s[8]; bf16x8 v; } au;
    au.s[0] = f2bf(x0.x); au.s[1] = f2bf(x0.y); au.s[2] = f2bf(x0.z); au.s[3] = f2bf(x0.w);
    au.s[4] = f2bf(x1.x); au.s[5] = f2bf(x1.y); au.s[6] = f2bf(x1.z); au.s[7] = f2bf(x1.w);
#pragma unroll
    for (int c = 0; c < 6; ++c) {
      BU bu;
      bu.u = wp4[(s * 6 + c) * 64 + lane];
      acc[c] = __builtin_amdgcn_mfma_f32_16x16x32_bf16(au.v, bu.v, acc[c], 0, 0, 0);
    }
  }
#pragma unroll
  for (int c = 0; c < 6; ++c) {
    int colv = c * 16 + lm;
#pragma unroll
    for (int r = 0; r < 4; ++r) {
      int orow = rt * 16 + quad * 4 + r;
      if (orow < N) Tb[(size_t)orow * 96 + colv] = f2bf(acc[c][r]);
    }
  }
}

// Dispatch 3: [0,NBIN) LDS-staged binning; [NBIN,NBIN+GB1) first half of gemm1.
__global__ __launch_bounds__(256) void bin_gemm1(const int* __restrict__ src,
                                                 const int* __restrict__ dst,
                                                 int* __restrict__ gcur,
                                                 int* __restrict__ packed, int E, int NB,
                                                 int NBIN, const float* __restrict__ x,
                                                 const unsigned short* __restrict__ Wp1,
                                                 unsigned short* __restrict__ Tb, int N) {
  __shared__ int lcnt[512];
  __shared__ int lstart[512];
  __shared__ int gbase[512];
  __shared__ int cur[512];
  __shared__ int stage[EB];
  int tid = threadIdx.x;
  if (blockIdx.x < NBIN) {
    lcnt[tid] = 0;
    lcnt[tid + 256] = 0;
    __syncthreads();
    int E4 = E >> 2;
    int base4 = blockIdx.x * (EB >> 2);
    int sv[16], dv[16];
    int nv = 0;
#pragma unroll
    for (int j = 0; j < 4; ++j) {
      int idx4 = base4 + j * 256 + tid;
      if (idx4 < E4 && idx4 < base4 + (EB >> 2)) {
        int4 s4 = ((const int4*)src)[idx4];
        int4 d4 = ((const int4*)dst)[idx4];
        sv[j * 4 + 0] = s4.x; dv[j * 4 + 0] = d4.x;
        sv[j * 4 + 1] = s4.y; dv[j * 4 + 1] = d4.y;
        sv[j * 4 + 2] = s4.z; dv[j * 4 + 2] = d4.z;
        sv[j * 4 + 3] = s4.w; dv[j * 4 + 3] = d4.w;
        nv = j * 4 + 4;
      }
    }
#pragma unroll
    for (int i = 0; i < 16; ++i)
      if (i < nv) atomicAdd(&lcnt[dv[i] >> 7], 1);
    bool last = (blockIdx.x == NBIN - 1);
    int tl = E & 3;
    if (last && tid == 0)
      for (int t = 0; t < tl; ++t) atomicAdd(&lcnt[dst[E4 * 4 + t] >> 7], 1);
    __syncthreads();
    lstart[tid] = lcnt[tid];
    lstart[tid + 256] = lcnt[tid + 256];
    __syncthreads();
    for (int off = 1; off < 512; off <<= 1) {
      int a0 = (tid >= off) ? lstart[tid - off] : 0;
      int i1 = tid + 256;
      int a1 = (i1 >= off) ? lstart[i1 - off] : 0;
      __syncthreads();
      lstart[tid] += a0;
      lstart[i1] += a1;
      __syncthreads();
    }
    int e0 = lstart[tid] - lcnt[tid];
    int e1 = lstart[tid + 256] - lcnt[tid + 256];
    __syncthreads();
    lstart[tid] = e0; cur[tid] = e0;
    lstart[tid + 256] = e1; cur[tid + 256] = e1;
    __syncthreads();
#pragma unroll
    for (int i = 0; i < 16; ++i)
      if (i < nv) {
        int b = dv[i] >> 7;
        int p = atomicAdd(&cur[b], 1);
        stage[p] = ((dv[i] & 127) << 16) | (sv[i] & 0xffff);
      }
    if (last && tid == 0)
      for (int t = 0; t < tl; ++t) {
        int d = dst[E4 * 4 + t], s = src[E4 * 4 + t];
        int p = atomicAdd(&cur[d >> 7], 1);
        stage[p] = ((d & 127) << 16) | (s & 0xffff);
      }
    if (lcnt[tid]) gbase[tid] = atomicAdd(&gcur[tid], lcnt[tid]);
    if (lcnt[tid + 256]) gbase[tid + 256] = atomicAdd(&gcur[tid + 256], lcnt[tid + 256]);
    __syncthreads();
    int meB = lstart[511] + lcnt[511];
    for (int i = tid; i < meB; i += 256) {
      int lo = 0, hi = 511;
      while (lo < hi) {
        int mid = (lo + hi + 1) >> 1;
        if (lstart[mid] <= i) lo = mid; else hi = mid - 1;
      }
      packed[gbase[lo] + (i - lstart[lo])] = stage[i];
    }
    return;
  }
  gemm1_tile(blockIdx.x - NBIN, tid, x, Wp1, Tb, N);
}

// Dispatch 4: [0,NB) per-bucket CSR finalize; [NB,NB+GB2) second half of gemm1.
__global__ __launch_bounds__(256) void build_gemm1(const int* __restrict__ packed,
                                                   const int* __restrict__ gstart,
                                                   int* __restrict__ row_ptr,
                                                   int* __restrict__ col, int N, int NB,
                                                   int GB1, const float* __restrict__ x,
                                                   const unsigned short* __restrict__ Wp1,
                                                   unsigned short* __restrict__ Tb) {
  int tid = threadIdx.x;
  if (blockIdx.x >= (unsigned)NB) {
    gemm1_tile(blockIdx.x - NB + GB1, tid, x, Wp1, Tb, N);
    return;
  }
  __shared__ int cnt[128];
  __shared__ int sm[128];
  int b = blockIdx.x;
  int gs = gstart[b], ge = gstart[b + 1];
  int me = ge - gs;
  int node0 = b << 7;
  int RL = N - node0;
  if (RL > 128) RL = 128;
  if (tid < 128) cnt[tid] = 0;
  __syncthreads();
  for (int i = tid; i < me; i += 256) atomicAdd(&cnt[packed[gs + i] >> 16], 1);
  __syncthreads();
  if (tid < 128) sm[tid] = cnt[tid];
  __syncthreads();
  for (int off = 1; off < 128; off <<= 1) {
    int u = (tid >= off && tid < 128) ? sm[tid - off] : 0;
    __syncthreads();
    if (tid < 128) sm[tid] += u;
    __syncthreads();
  }
  if (tid < 128) {
    int excl = gs + sm[tid] - cnt[tid];
    cnt[tid] = excl;
    if (tid < RL) row_ptr[node0 + tid] = excl;
  }
  __syncthreads();
  for (int i = tid; i < me; i += 256) {
    int pk = packed[gs + i];
    int p = atomicAdd(&cnt[pk >> 16], 1);
    col[p] = pk & 0xffff;
  }
}

// ================= Fused aggregation + GEMM =================
// Block owns 64 nodes; col + row_ptr staged in LDS. Phase A: unroll x4 (x8
// spilled under the VGPR cap and regressed — R10), fits-flag hoisted. Phase B:
// per-step B reload. launch_bounds (256,8): LDS 19.8KB allows 8 blocks/CU;
// live ranges ~45 should fit 64 VGPR (R12 experiment; revert if regressed).

template <int NCT, int MOUT, int MVALID>
__global__ __launch_bounds__(256, 8) void fused_agg_gemm(
    const unsigned short* __restrict__ tin, const int* __restrict__ row_ptr,
    const int* __restrict__ col, const float* __restrict__ bias,
    const unsigned short* __restrict__ Wp, unsigned short* __restrict__ outp, int N) {
  constexpr int LST = 104;   // bf16 units per LDS row
  constexpr int CAP = 1536;  // staged edges (mean 1024, ~16 sigma)
  __shared__ unsigned short sH[64 * LST];
  __shared__ int scol[CAP];
  __shared__ int srp[65];
  int tid = threadIdx.x;
  int node0 = blockIdx.x * 64;
  int nloc = N - node0;
  if (nloc > 64) nloc = 64;
  if (tid <= nloc) srp[tid] = row_ptr[node0 + tid];
  __syncthreads();
  int gs = srp[0];
  int me = srp[nloc] - gs;
  for (int i = tid; i < me && i < CAP; i += 256) scol[i] = col[gs + i];
  __syncthreads();
  bool fits = (me <= CAP);

  // ---- Phase A: aggregate 64 nodes x 12 chunks of 8 bf16, unroll x4 ----
#pragma unroll
  for (int it = 0; it < 3; ++it) {
    int u = tid + it * 256;
    int nl = u / 12;
    int c = u - nl * 12;
    if (nl < nloc) {
      int beg = srp[nl] - gs;
      int end = srp[nl + 1] - gs;
      const unsigned short* tc = tin + 8 * c;
      float a0 = 0.f, a1 = 0.f, a2 = 0.f, a3 = 0.f, a4 = 0.f, a5 = 0.f, a6 = 0.f, a7 = 0.f;
      if (fits) {
        int e = beg;
        for (; e + 3 < end; e += 4) {
          int s0 = scol[e], s1 = scol[e + 1], s2 = scol[e + 2], s3 = scol[e + 3];
          uint4 u0 = *(const uint4*)(tc + (size_t)s0 * 96);
          uint4 u1 = *(const uint4*)(tc + (size_t)s1 * 96);
          uint4 u2 = *(const uint4*)(tc + (size_t)s2 * 96);
          uint4 u3 = *(const uint4*)(tc + (size_t)s3 * 96);
          ACC8(u0); ACC8(u1); ACC8(u2); ACC8(u3);
        }
        for (; e < end; ++e) {
          int s0 = scol[e];
          uint4 u4 = *(const uint4*)(tc + (size_t)s0 * 96);
          ACC8(u4);
        }
      } else {  // ~never: degree mass above CAP
        for (int e = beg; e < end; ++e) {
          int s0 = col[gs + e];
          uint4 u4 = *(const uint4*)(tc + (size_t)s0 * 96);
          ACC8(u4);
        }
      }
      const float* b = bias + 8 * c;
      union { unsigned short s[8]; uint4 u; } pk;
      pk.s[0] = f2bf(fmaxf(a0 + b[0], 0.f));
      pk.s[1] = f2bf(fmaxf(a1 + b[1], 0.f));
      pk.s[2] = f2bf(fmaxf(a2 + b[2], 0.f));
      pk.s[3] = f2bf(fmaxf(a3 + b[3], 0.f));
      pk.s[4] = f2bf(fmaxf(a4 + b[4], 0.f));
      pk.s[5] = f2bf(fmaxf(a5 + b[5], 0.f));
      pk.s[6] = f2bf(fmaxf(a6 + b[6], 0.f));
      pk.s[7] = f2bf(fmaxf(a7 + b[7], 0.f));
      *(uint4*)&sH[nl * LST + c * 8] = pk.u;
    }
  }
  __syncthreads();

  // ---- Phase B: MFMA tile per wave; per-step B-frag reload ----
  int wid = tid >> 6;
  int lane = tid & 63;
  int rt16 = wid * 16;
  if (node0 + rt16 >= N) return;
  int quad = lane >> 4;
  int lm = lane & 15;
  union BU { uint4 u; bf16x8 v; };
  f32x4 acc[NCT];
#pragma unroll
  for (int c = 0; c < NCT; ++c) acc[c] = (f32x4){0.f, 0.f, 0.f, 0.f};
  const uint4* wp4 = (const uint4*)Wp;
#pragma unroll
  for (int s = 0; s < 3; ++s) {
    BU au;
    au.u = *(const uint4*)&sH[(rt16 + lm) * LST + s * 32 + quad * 8];
#pragma unroll
    for (int c = 0; c < NCT; ++c) {
      BU bu;
      bu.u = wp4[(s * NCT + c) * 64 + lane];
      acc[c] = __builtin_amdgcn_mfma_f32_16x16x32_bf16(au.v, bu.v, acc[c], 0, 0, 0);
    }
  }
#pragma unroll
  for (int c = 0; c < NCT; ++c) {
    int colv = c * 16 + lm;
    if (colv >= MVALID) continue;
#pragma unroll
    for (int r = 0; r < 4; ++r) {
      int orow = node0 + rt16 + quad * 4 + r;
      if (orow < N) outp[(size_t)orow * MOUT + colv] = f2bf(acc[c][r]);
    }
  }
}

// Layer-3 aggregation (bf16 in, row stride 64 = 128 B / 2 cache lines) +
// bias + log_softmax. Block = 16 nodes; 16-lane group per node; lanes 0..9
// hold 4 classes each (uint2).

__global__ __launch_bounds__(256) void agg_lsm_bf16(const unsigned short* __restrict__ t,
                                                    const int* __restrict__ row_ptr,
                                                    const int* __restrict__ col,
                                                    const float* __restrict__ bias,
                                                    float* __restrict__ out, int N) {
  constexpr int CAPL = 1024;  // staged edges (mean 256)
  __shared__ int scol[CAPL];
  __shared__ int srp[17];
  int tid = threadIdx.x;
  int node0 = blockIdx.x * 16;
  int nloc = N - node0;
  if (nloc > 16) nloc = 16;
  if (tid <= nloc) srp[tid] = row_ptr[node0 + tid];
  __syncthreads();
  int gs = srp[0];
  int me = srp[nloc] - gs;
  for (int i = tid; i < me && i < CAPL; i += 256) scol[i] = col[gs + i];
  __syncthreads();
  bool fits = (me <= CAPL);

  int nl = tid >> 4;
  int c = tid & 15;  // 0..9 active
  bool act = (c < 10) && (nl < nloc);
  int ceff = (c < 10) ? c : 0;
  const unsigned short* tc = t + 4 * ceff;
  float v0 = 0.f, v1 = 0.f, v2 = 0.f, v3 = 0.f;
  if (act) {
    int beg = srp[nl] - gs;
    int end = srp[nl + 1] - gs;
    if (fits) {
      int e = beg;
      for (; e + 3 < end; e += 4) {
        int s0 = scol[e], s1 = scol[e + 1], s2 = scol[e + 2], s3 = scol[e + 3];
        uint2 u = *(const uint2*)(tc + (size_t)s0 * 64);
        uint2 w = *(const uint2*)(tc + (size_t)s1 * 64);
        uint2 y = *(const uint2*)(tc + (size_t)s2 * 64);
        uint2 z = *(const uint2*)(tc + (size_t)s3 * 64);
        v0 += bflo(u.x); v1 += bfhi(u.x); v2 += bflo(u.y); v3 += bfhi(u.y);
        v0 += bflo(w.x); v1 += bfhi(w.x); v2 += bflo(w.y); v3 += bfhi(w.y);
        v0 += bflo(y.x); v1 += bfhi(y.x); v2 += bflo(y.y); v3 += bfhi(y.y);
        v0 += bflo(z.x); v1 += bfhi(z.x); v2 += bflo(z.y); v3 += bfhi(z.y);
      }
      for (; e < end; ++e) {
        int s0 = scol[e];
        uint2 u = *(const uint2*)(tc + (size_t)s0 * 64);
        v0 += bflo(u.x); v1 += bfhi(u.x); v2 += bflo(u.y); v3 += bfhi(u.y);
      }
    } else {
      for (int e = beg; e < end; ++e) {
        int s0 = col[gs + e];
        uint2 u = *(const uint2*)(tc + (size_t)s0 * 64);
        v0 += bflo(u.x); v1 += bfhi(u.x); v2 += bflo(u.y); v3 += bfhi(u.y);
      }
    }
  }
  const float* bb = bias + 4 * ceff;
  v0 += bb[0]; v1 += bb[1]; v2 += bb[2]; v3 += bb[3];
  float m = act ? fmaxf(fmaxf(v0, v1), fmaxf(v2, v3)) : -__builtin_inff();
#pragma unroll
  for (int off = 8; off; off >>= 1) m = fmaxf(m, __shfl_xor(m, off, 64));
  float ex = act ? (__expf(v0 - m) + __expf(v1 - m) + __expf(v2 - m) + __expf(v3 - m)) : 0.f;
#pragma unroll
  for (int off = 8; off; off >>= 1) ex += __shfl_xor(ex, off, 64);
  if (act) {
    int node = node0 + nl;
    float l = m + __logf(ex);
    float* o = out + (size_t)node * 40 + 4 * c;
    o[0] = v0 - l; o[1] = v1 - l; o[2] = v2 - l; o[3] = v3 - l;
  }
}

// ================= Launch =================

extern "C" void kernel_launch(void* const* d_in, const int* in_sizes, int n_in,
                              void* d_out, int out_size, void* d_ws, size_t ws_size,
                              hipStream_t stream) {
  const float* x  = (const float*)d_in[0];
  const float* W1 = (const float*)d_in[1];
  const float* b1 = (const float*)d_in[2];
  const float* W2 = (const float*)d_in[3];
  const float* b2 = (const float*)d_in[4];
  const float* W3 = (const float*)d_in[5];
  const float* b3 = (const float*)d_in[6];
  const int* edge = (const int*)d_in[7];

  int N = in_sizes[0] / 128;  // 50000
  int E = in_sizes[7] / 2;    // 800000
  const int* srcp = edge;
  const int* dstp = edge + E;

  char* p = (char*)d_ws;
  auto alloc = [&](size_t bytes) {
    char* r = p;
    p += (bytes + 255) & ~size_t(255);
    return r;
  };
  int NB = (N + 127) >> 7;  // 391 buckets of 128 nodes
  int* partial = (int*)alloc((size_t)CB * 512 * 4);
  int* gstart  = (int*)alloc((size_t)(NB + 1) * 4);
  int* gcur    = (int*)alloc((size_t)NB * 4);
  int* row_ptr = (int*)alloc((size_t)(N + 1) * 4);
  int* packed  = (int*)alloc((size_t)E * 4);
  int* col     = (int*)alloc((size_t)E * 4);
  unsigned short* Wp1 = (unsigned short*)alloc(1536 * 8 * 2);
  unsigned short* Wp2 = (unsigned short*)alloc(1152 * 8 * 2);
  unsigned short* Wp3 = (unsigned short*)alloc(576 * 8 * 2);
  unsigned short* Tb  = (unsigned short*)alloc((size_t)N * 96 * 2);   // t1
  unsigned short* T2b = (unsigned short*)alloc((size_t)N * 96 * 2);   // t2
  unsigned short* T3b = (unsigned short*)alloc((size_t)N * 64 * 2);   // t3, 128-B rows

  int NBIN = (E + EB - 1) / EB;      // 196 binning blocks
  int GB = ((N + 15) / 16 + 3) / 4;  // 782 gemm1 blocks (4 row-tiles each)
  int GB1 = GB / 2;                  // first half with bin (d3)
  int GB2 = GB - GB1;                // second half with build (d4)
  int FB = (N + 63) / 64;            // fused blocks (64 nodes each)

  // 1: bucket count + W1/W2/W3 pack
  count_pack<<<CB + 13, 256, 0, stream>>>(dstp, partial, E, W1, W2, W3, Wp1, Wp2, Wp3);
  // 2: scan bucket totals
  scan_kernel<<<1, 256, 0, stream>>>(partial, gstart, gcur, row_ptr, NB, N, E);
  // 3: LDS-staged bin + gemm1 rows [0, GB1*64)
  bin_gemm1<<<NBIN + GB1, 256, 0, stream>>>(srcp, dstp, gcur, packed, E, NB, NBIN,
                                            x, Wp1, Tb, N);
  // 4: per-bucket CSR finalize + gemm1 rows [GB1*64, N)
  build_gemm1<<<NB + GB2, 256, 0, stream>>>(packed, gstart, row_ptr, col, N, NB,
                                            GB1, x, Wp1, Tb);
  // 5: t2 = relu(agg(t1)+b1) @ W2
  fused_agg_gemm<6, 96, 96><<<FB, 256, 0, stream>>>(Tb, row_ptr, col, b1, Wp2, T2b, N);
  // 6: t3 = relu(agg(t2)+b2) @ W3 (row stride 64)
  fused_agg_gemm<3, 64, 40><<<FB, 256, 0, stream>>>(T2b, row_ptr, col, b2, Wp3, T3b, N);
  // 7: out = log_softmax(agg(t3) + b3)
  agg_lsm_bf16<<<(N + 15) / 16, 256, 0, stream>>>(T3b, row_ptr, col, b3, (float*)d_out, N);
}

// Round 13
// 188.607 us; speedup vs baseline: 1.1151x; 1.0184x over previous
//
#include <hip/hip_runtime.h>
#include <math.h>

typedef __attribute__((ext_vector_type(8))) short bf16x8;
typedef __attribute__((ext_vector_type(4))) float f32x4;

__device__ __forceinline__ unsigned short f2bf(float f) {
  unsigned u = __float_as_uint(f);
  u += 0x7fffu + ((u >> 16) & 1u);  // round-to-nearest-even
  return (unsigned short)(u >> 16);
}
__device__ __forceinline__ float bflo(unsigned u) { return __uint_as_float(u << 16); }
__device__ __forceinline__ float bfhi(unsigned u) { return __uint_as_float(u & 0xffff0000u); }

#define ACC8(U)                                           \
  a0 += bflo(U.x); a1 += bfhi(U.x); a2 += bflo(U.y); a3 += bfhi(U.y); \
  a4 += bflo(U.z); a5 += bfhi(U.z); a6 += bflo(U.w); a7 += bfhi(U.w)

// ================= CSR via two-level bucket binning =================
// Buckets of 128 nodes (NB = ceil(N/128) = 391 <= 512). packed edge =
// (d_local<<16)|src, stored in FIXED per-bucket slots (SLOT each) so binning
// needs no global scan first. Requires N <= 65536 — N = 50000 here.

constexpr int CB = 64;      // histogram blocks
constexpr int EB = 4096;    // edges per binning block
constexpr int SLOT = 3072;  // slot capacity per bucket (mean 2048, ~23 sigma)

// Dispatch 1: [0,CB) histogram partials; [CB,CB+13) pack W1/W2/W3 to MFMA
// B-fragment order; block CB+13 zeroes per-bucket cursors.
__global__ __launch_bounds__(256) void count_pack(const int* __restrict__ dst,
                                                  int* __restrict__ partial, int E, int NB,
                                                  int* __restrict__ cursor,
                                                  const float* __restrict__ W1,
                                                  const float* __restrict__ W2,
                                                  const float* __restrict__ W3,
                                                  unsigned short* __restrict__ Wp1,
                                                  unsigned short* __restrict__ Wp2,
                                                  unsigned short* __restrict__ Wp3) {
  int tid = threadIdx.x;
  if (blockIdx.x < CB) {
    __shared__ int bkt[512];
    bkt[tid] = 0;
    bkt[tid + 256] = 0;
    __syncthreads();
    int E4 = E >> 2;
    const int4* d4 = (const int4*)dst;
    for (int i = blockIdx.x * 256 + tid; i < E4; i += CB * 256) {
      int4 d = d4[i];
      atomicAdd(&bkt[d.x >> 7], 1);
      atomicAdd(&bkt[d.y >> 7], 1);
      atomicAdd(&bkt[d.z >> 7], 1);
      atomicAdd(&bkt[d.w >> 7], 1);
    }
    if (blockIdx.x == 0 && tid < (E & 3)) atomicAdd(&bkt[dst[E4 * 4 + tid] >> 7], 1);
    __syncthreads();
    partial[blockIdx.x * 512 + tid] = bkt[tid];
    partial[blockIdx.x * 512 + tid + 256] = bkt[tid + 256];
    return;
  }
  if (blockIdx.x == CB + 13) {  // zero slot cursors
    for (int i = tid; i < NB; i += 256) cursor[i] = 0;
    return;
  }
  int gid = (blockIdx.x - CB) * 256 + tid;
  const float* W;
  unsigned short* Wp;
  int t, NCTT, M, MV;
  if (gid < 1536) {            // W1: 4 ksteps * 6 coltiles * 64 lanes
    W = W1; Wp = Wp1; t = gid; NCTT = 6; M = 96; MV = 96;
  } else if (gid < 2688) {     // W2: 3 * 6 * 64
    W = W2; Wp = Wp2; t = gid - 1536; NCTT = 6; M = 96; MV = 96;
  } else if (gid < 3264) {     // W3: 3 * 3 * 64 (cols >= 40 zero-padded)
    W = W3; Wp = Wp3; t = gid - 2688; NCTT = 3; M = 40; MV = 40;
  } else {
    return;
  }
  int lane = t & 63;
  int frag = t >> 6;
  int s = frag / NCTT;
  int ct = frag - s * NCTT;
  int colv = ct * 16 + (lane & 15);
  int k0 = s * 32 + (lane >> 4) * 8;
  union { unsigned short s[8]; uint4 u; } pk;
#pragma unroll
  for (int j = 0; j < 8; ++j) {
    float v = (colv < MV) ? W[(k0 + j) * M + colv] : 0.f;
    pk.s[j] = f2bf(v);
  }
  ((uint4*)Wp)[t] = pk.u;
}

// gemm1 row-tile worker: block bx covers rows [bx*64, bx*64+64).
__device__ __forceinline__ void gemm1_tile(int bx, int tid, const float* __restrict__ x,
                                           const unsigned short* __restrict__ Wp1,
                                           unsigned short* __restrict__ Tb, int N) {
  int wid = tid >> 6;
  int lane = tid & 63;
  int rt = bx * 4 + wid;
  if (rt * 16 >= N) return;
  int quad = lane >> 4;
  int lm = lane & 15;
  union BU { uint4 u; bf16x8 v; };
  f32x4 acc[6];
#pragma unroll
  for (int c = 0; c < 6; ++c) acc[c] = (f32x4){0.f, 0.f, 0.f, 0.f};
  int row = rt * 16 + lm;
  if (row >= N) row = N - 1;  // safe dup read; epilogue guards rows
  const uint4* wp4 = (const uint4*)Wp1;
#pragma unroll
  for (int s = 0; s < 4; ++s) {
    int k0 = s * 32 + quad * 8;
    const float* Af = x + (size_t)row * 128 + k0;
    float4 x0 = *(const float4*)(Af);
    float4 x1 = *(const float4*)(Af + 4);
    union { unsigned short s[8]; bf16x8 v; } au;
    au.s[0] = f2bf(x0.x); au.s[1] = f2bf(x0.y); au.s[2] = f2bf(x0.z); au.s[3] = f2bf(x0.w);
    au.s[4] = f2bf(x1.x); au.s[5] = f2bf(x1.y); au.s[6] = f2bf(x1.z); au.s[7] = f2bf(x1.w);
#pragma unroll
    for (int c = 0; c < 6; ++c) {
      BU bu;
      bu.u = wp4[(s * 6 + c) * 64 + lane];
      acc[c] = __builtin_amdgcn_mfma_f32_16x16x32_bf16(au.v, bu.v, acc[c], 0, 0, 0);
    }
  }
#pragma unroll
  for (int c = 0; c < 6; ++c) {
    int colv = c * 16 + lm;
#pragma unroll
    for (int r = 0; r < 4; ++r) {
      int orow = rt * 16 + quad * 4 + r;
      if (orow < N) Tb[(size_t)orow * 96 + colv] = f2bf(acc[c][r]);
    }
  }
}

// Dispatch 2: [0,NBIN) LDS-staged binning into fixed slots; block NBIN = scan
// of bucket totals -> gstart (for build) ; [NBIN+1, ..) first half of gemm1.
// All three roles depend only on dispatch 1.
__global__ __launch_bounds__(256) void bin_scan_gemm1(
    const int* __restrict__ src, const int* __restrict__ dst, int* __restrict__ cursor,
    int* __restrict__ packed, const int* __restrict__ partial, int* __restrict__ gstart,
    int* __restrict__ row_ptr, int E, int NB, int NBIN, int N,
    const float* __restrict__ x, const unsigned short* __restrict__ Wp1,
    unsigned short* __restrict__ Tb) {
  __shared__ int lcnt[512];
  __shared__ int lstart[512];
  __shared__ int gbase[512];
  __shared__ int cur[512];
  __shared__ int stage[EB];
  int tid = threadIdx.x;
  if (blockIdx.x < (unsigned)NBIN) {
    lcnt[tid] = 0;
    lcnt[tid + 256] = 0;
    __syncthreads();
    int E4 = E >> 2;
    int base4 = blockIdx.x * (EB >> 2);
    int sv[16], dv[16];
    int nv = 0;
#pragma unroll
    for (int j = 0; j < 4; ++j) {
      int idx4 = base4 + j * 256 + tid;
      if (idx4 < E4 && idx4 < base4 + (EB >> 2)) {
        int4 s4 = ((const int4*)src)[idx4];
        int4 d4 = ((const int4*)dst)[idx4];
        sv[j * 4 + 0] = s4.x; dv[j * 4 + 0] = d4.x;
        sv[j * 4 + 1] = s4.y; dv[j * 4 + 1] = d4.y;
        sv[j * 4 + 2] = s4.z; dv[j * 4 + 2] = d4.z;
        sv[j * 4 + 3] = s4.w; dv[j * 4 + 3] = d4.w;
        nv = j * 4 + 4;
      }
    }
#pragma unroll
    for (int i = 0; i < 16; ++i)
      if (i < nv) atomicAdd(&lcnt[dv[i] >> 7], 1);
    bool last = (blockIdx.x == (unsigned)(NBIN - 1));
    int tl = E & 3;
    if (last && tid == 0)
      for (int t = 0; t < tl; ++t) atomicAdd(&lcnt[dst[E4 * 4 + t] >> 7], 1);
    __syncthreads();
    // exclusive scan of 512 local counts
    lstart[tid] = lcnt[tid];
    lstart[tid + 256] = lcnt[tid + 256];
    __syncthreads();
    for (int off = 1; off < 512; off <<= 1) {
      int a0 = (tid >= off) ? lstart[tid - off] : 0;
      int i1 = tid + 256;
      int a1 = (i1 >= off) ? lstart[i1 - off] : 0;
      __syncthreads();
      lstart[tid] += a0;
      lstart[i1] += a1;
      __syncthreads();
    }
    int e0 = lstart[tid] - lcnt[tid];
    int e1 = lstart[tid + 256] - lcnt[tid + 256];
    __syncthreads();
    lstart[tid] = e0; cur[tid] = e0;
    lstart[tid + 256] = e1; cur[tid + 256] = e1;
    __syncthreads();
    // place into LDS stage (bucket-sorted)
#pragma unroll
    for (int i = 0; i < 16; ++i)
      if (i < nv) {
        int b = dv[i] >> 7;
        int p = atomicAdd(&cur[b], 1);
        stage[p] = ((dv[i] & 127) << 16) | (sv[i] & 0xffff);
      }
    if (last && tid == 0)
      for (int t = 0; t < tl; ++t) {
        int d = dst[E4 * 4 + t], s = src[E4 * 4 + t];
        int p = atomicAdd(&cur[d >> 7], 1);
        stage[p] = ((d & 127) << 16) | (s & 0xffff);
      }
    // reserve slot-local runs (cursor starts at 0; slots are bucket-fixed)
    if (lcnt[tid]) gbase[tid] = atomicAdd(&cursor[tid], lcnt[tid]);
    if (lcnt[tid + 256]) gbase[tid + 256] = atomicAdd(&cursor[tid + 256], lcnt[tid + 256]);
    __syncthreads();
    // dense run writes into per-bucket slots; bucket via binary search
    int meB = lstart[511] + lcnt[511];
    for (int i = tid; i < meB; i += 256) {
      int lo = 0, hi = 511;
      while (lo < hi) {
        int mid = (lo + hi + 1) >> 1;
        if (lstart[mid] <= i) lo = mid; else hi = mid - 1;
      }
      packed[(size_t)lo * SLOT + gbase[lo] + (i - lstart[lo])] = stage[i];
    }
    return;
  }
  if (blockIdx.x == (unsigned)NBIN) {
    // scan of bucket totals -> gstart (global col/row_ptr offsets for build)
    int s0 = 0, s1 = 0;
#pragma unroll 8
    for (int i = 0; i < CB; ++i) {
      s0 += partial[i * 512 + tid];
      s1 += partial[i * 512 + tid + 256];
    }
    lcnt[tid] = s0;
    lcnt[tid + 256] = s1;
    __syncthreads();
    for (int off = 1; off < 512; off <<= 1) {
      int a0 = (tid >= off) ? lcnt[tid - off] : 0;
      int i1 = tid + 256;
      int a1 = (i1 >= off) ? lcnt[i1 - off] : 0;
      __syncthreads();
      lcnt[tid] += a0;
      lcnt[i1] += a1;
      __syncthreads();
    }
    int e0 = lcnt[tid] - s0;
    int e1 = lcnt[tid + 256] - s1;
    if (tid < NB) gstart[tid] = e0;
    int b1 = tid + 256;
    if (b1 < NB) gstart[b1] = e1;
    if (tid == 255) gstart[NB] = lcnt[511];
    if (tid == 0) row_ptr[N] = E;
    return;
  }
  gemm1_tile(blockIdx.x - NBIN - 1, tid, x, Wp1, Tb, N);
}

// Dispatch 3: [0,NB) per-bucket CSR finalize (reads fixed slots, writes
// compacted col + row_ptr); [NB,..) second half of gemm1.
__global__ __launch_bounds__(256) void build_gemm1(const int* __restrict__ packed,
                                                   const int* __restrict__ gstart,
                                                   int* __restrict__ row_ptr,
                                                   int* __restrict__ col, int N, int NB,
                                                   int GB1, const float* __restrict__ x,
                                                   const unsigned short* __restrict__ Wp1,
                                                   unsigned short* __restrict__ Tb) {
  int tid = threadIdx.x;
  if (blockIdx.x >= (unsigned)NB) {
    gemm1_tile(blockIdx.x - NB + GB1, tid, x, Wp1, Tb, N);
    return;
  }
  __shared__ int cnt[128];
  __shared__ int sm[128];
  int b = blockIdx.x;
  int gs = gstart[b], ge = gstart[b + 1];
  int me = ge - gs;
  const int* pslot = packed + (size_t)b * SLOT;
  int node0 = b << 7;
  int RL = N - node0;
  if (RL > 128) RL = 128;
  if (tid < 128) cnt[tid] = 0;
  __syncthreads();
  for (int i = tid; i < me; i += 256) atomicAdd(&cnt[pslot[i] >> 16], 1);
  __syncthreads();
  if (tid < 128) sm[tid] = cnt[tid];
  __syncthreads();
  for (int off = 1; off < 128; off <<= 1) {
    int u = (tid >= off && tid < 128) ? sm[tid - off] : 0;
    __syncthreads();
    if (tid < 128) sm[tid] += u;
    __syncthreads();
  }
  if (tid < 128) {
    int excl = gs + sm[tid] - cnt[tid];
    cnt[tid] = excl;  // repurpose as cursor
    if (tid < RL) row_ptr[node0 + tid] = excl;
  }
  __syncthreads();
  for (int i = tid; i < me; i += 256) {
    int pk = pslot[i];
    int p = atomicAdd(&cnt[pk >> 16], 1);
    col[p] = pk & 0xffff;
  }
}

// ================= Fused aggregation + GEMM =================
// Block owns 64 nodes; col + row_ptr staged in LDS. Phase A: unroll x4 (x8
// spilled under the VGPR cap and regressed — R10), fits-flag hoisted. Phase B:
// per-step B reload. launch_bounds (256,8): LDS 19.8KB allows 8 blocks/CU.

template <int NCT, int MOUT, int MVALID>
__global__ __launch_bounds__(256, 8) void fused_agg_gemm(
    const unsigned short* __restrict__ tin, const int* __restrict__ row_ptr,
    const int* __restrict__ col, const float* __restrict__ bias,
    const unsigned short* __restrict__ Wp, unsigned short* __restrict__ outp, int N) {
  constexpr int LST = 104;   // bf16 units per LDS row
  constexpr int CAP = 1536;  // staged edges (mean 1024, ~16 sigma)
  __shared__ unsigned short sH[64 * LST];
  __shared__ int scol[CAP];
  __shared__ int srp[65];
  int tid = threadIdx.x;
  int node0 = blockIdx.x * 64;
  int nloc = N - node0;
  if (nloc > 64) nloc = 64;
  if (tid <= nloc) srp[tid] = row_ptr[node0 + tid];
  __syncthreads();
  int gs = srp[0];
  int me = srp[nloc] - gs;
  for (int i = tid; i < me && i < CAP; i += 256) scol[i] = col[gs + i];
  __syncthreads();
  bool fits = (me <= CAP);

  // ---- Phase A: aggregate 64 nodes x 12 chunks of 8 bf16, unroll x4 ----
#pragma unroll
  for (int it = 0; it < 3; ++it) {
    int u = tid + it * 256;
    int nl = u / 12;
    int c = u - nl * 12;
    if (nl < nloc) {
      int beg = srp[nl] - gs;
      int end = srp[nl + 1] - gs;
      const unsigned short* tc = tin + 8 * c;
      float a0 = 0.f, a1 = 0.f, a2 = 0.f, a3 = 0.f, a4 = 0.f, a5 = 0.f, a6 = 0.f, a7 = 0.f;
      if (fits) {
        int e = beg;
        for (; e + 3 < end; e += 4) {
          int s0 = scol[e], s1 = scol[e + 1], s2 = scol[e + 2], s3 = scol[e + 3];
          uint4 u0 = *(const uint4*)(tc + (size_t)s0 * 96);
          uint4 u1 = *(const uint4*)(tc + (size_t)s1 * 96);
          uint4 u2 = *(const uint4*)(tc + (size_t)s2 * 96);
          uint4 u3 = *(const uint4*)(tc + (size_t)s3 * 96);
          ACC8(u0); ACC8(u1); ACC8(u2); ACC8(u3);
        }
        for (; e < end; ++e) {
          int s0 = scol[e];
          uint4 u4 = *(const uint4*)(tc + (size_t)s0 * 96);
          ACC8(u4);
        }
      } else {  // ~never: degree mass above CAP
        for (int e = beg; e < end; ++e) {
          int s0 = col[gs + e];
          uint4 u4 = *(const uint4*)(tc + (size_t)s0 * 96);
          ACC8(u4);
        }
      }
      const float* b = bias + 8 * c;
      union { unsigned short s[8]; uint4 u; } pk;
      pk.s[0] = f2bf(fmaxf(a0 + b[0], 0.f));
      pk.s[1] = f2bf(fmaxf(a1 + b[1], 0.f));
      pk.s[2] = f2bf(fmaxf(a2 + b[2], 0.f));
      pk.s[3] = f2bf(fmaxf(a3 + b[3], 0.f));
      pk.s[4] = f2bf(fmaxf(a4 + b[4], 0.f));
      pk.s[5] = f2bf(fmaxf(a5 + b[5], 0.f));
      pk.s[6] = f2bf(fmaxf(a6 + b[6], 0.f));
      pk.s[7] = f2bf(fmaxf(a7 + b[7], 0.f));
      *(uint4*)&sH[nl * LST + c * 8] = pk.u;
    }
  }
  __syncthreads();

  // ---- Phase B: MFMA tile per wave; per-step B-frag reload ----
  int wid = tid >> 6;
  int lane = tid & 63;
  int rt16 = wid * 16;
  if (node0 + rt16 >= N) return;
  int quad = lane >> 4;
  int lm = lane & 15;
  union BU { uint4 u; bf16x8 v; };
  f32x4 acc[NCT];
#pragma unroll
  for (int c = 0; c < NCT; ++c) acc[c] = (f32x4){0.f, 0.f, 0.f, 0.f};
  const uint4* wp4 = (const uint4*)Wp;
#pragma unroll
  for (int s = 0; s < 3; ++s) {
    BU au;
    au.u = *(const uint4*)&sH[(rt16 + lm) * LST + s * 32 + quad * 8];
#pragma unroll
    for (int c = 0; c < NCT; ++c) {
      BU bu;
      bu.u = wp4[(s * NCT + c) * 64 + lane];
      acc[c] = __builtin_amdgcn_mfma_f32_16x16x32_bf16(au.v, bu.v, acc[c], 0, 0, 0);
    }
  }
#pragma unroll
  for (int c = 0; c < NCT; ++c) {
    int colv = c * 16 + lm;
    if (colv >= MVALID) continue;
#pragma unroll
    for (int r = 0; r < 4; ++r) {
      int orow = node0 + rt16 + quad * 4 + r;
      if (orow < N) outp[(size_t)orow * MOUT + colv] = f2bf(acc[c][r]);
    }
  }
}

// Layer-3 aggregation (bf16 in, row stride 64 = 128 B / 2 cache lines) +
// bias + log_softmax. Block = 16 nodes; 16-lane group per node; lanes 0..9
// hold 4 classes each (uint2).

__global__ __launch_bounds__(256) void agg_lsm_bf16(const unsigned short* __restrict__ t,
                                                    const int* __restrict__ row_ptr,
                                                    const int* __restrict__ col,
                                                    const float* __restrict__ bias,
                                                    float* __restrict__ out, int N) {
  constexpr int CAPL = 1024;  // staged edges (mean 256)
  __shared__ int scol[CAPL];
  __shared__ int srp[17];
  int tid = threadIdx.x;
  int node0 = blockIdx.x * 16;
  int nloc = N - node0;
  if (nloc > 16) nloc = 16;
  if (tid <= nloc) srp[tid] = row_ptr[node0 + tid];
  __syncthreads();
  int gs = srp[0];
  int me = srp[nloc] - gs;
  for (int i = tid; i < me && i < CAPL; i += 256) scol[i] = col[gs + i];
  __syncthreads();
  bool fits = (me <= CAPL);

  int nl = tid >> 4;
  int c = tid & 15;  // 0..9 active
  bool act = (c < 10) && (nl < nloc);
  int ceff = (c < 10) ? c : 0;
  const unsigned short* tc = t + 4 * ceff;
  float v0 = 0.f, v1 = 0.f, v2 = 0.f, v3 = 0.f;
  if (act) {
    int beg = srp[nl] - gs;
    int end = srp[nl + 1] - gs;
    if (fits) {
      int e = beg;
      for (; e + 3 < end; e += 4) {
        int s0 = scol[e], s1 = scol[e + 1], s2 = scol[e + 2], s3 = scol[e + 3];
        uint2 u = *(const uint2*)(tc + (size_t)s0 * 64);
        uint2 w = *(const uint2*)(tc + (size_t)s1 * 64);
        uint2 y = *(const uint2*)(tc + (size_t)s2 * 64);
        uint2 z = *(const uint2*)(tc + (size_t)s3 * 64);
        v0 += bflo(u.x); v1 += bfhi(u.x); v2 += bflo(u.y); v3 += bfhi(u.y);
        v0 += bflo(w.x); v1 += bfhi(w.x); v2 += bflo(w.y); v3 += bfhi(w.y);
        v0 += bflo(y.x); v1 += bfhi(y.x); v2 += bflo(y.y); v3 += bfhi(y.y);
        v0 += bflo(z.x); v1 += bfhi(z.x); v2 += bflo(z.y); v3 += bfhi(z.y);
      }
      for (; e < end; ++e) {
        int s0 = scol[e];
        uint2 u = *(const uint2*)(tc + (size_t)s0 * 64);
        v0 += bflo(u.x); v1 += bfhi(u.x); v2 += bflo(u.y); v3 += bfhi(u.y);
      }
    } else {
      for (int e = beg; e < end; ++e) {
        int s0 = col[gs + e];
        uint2 u = *(const uint2*)(tc + (size_t)s0 * 64);
        v0 += bflo(u.x); v1 += bfhi(u.x); v2 += bflo(u.y); v3 += bfhi(u.y);
      }
    }
  }
  const float* bb = bias + 4 * ceff;
  v0 += bb[0]; v1 += bb[1]; v2 += bb[2]; v3 += bb[3];
  float m = act ? fmaxf(fmaxf(v0, v1), fmaxf(v2, v3)) : -__builtin_inff();
#pragma unroll
  for (int off = 8; off; off >>= 1) m = fmaxf(m, __shfl_xor(m, off, 64));
  float ex = act ? (__expf(v0 - m) + __expf(v1 - m) + __expf(v2 - m) + __expf(v3 - m)) : 0.f;
#pragma unroll
  for (int off = 8; off; off >>= 1) ex += __shfl_xor(ex, off, 64);
  if (act) {
    int node = node0 + nl;
    float l = m + __logf(ex);
    float* o = out + (size_t)node * 40 + 4 * c;
    o[0] = v0 - l; o[1] = v1 - l; o[2] = v2 - l; o[3] = v3 - l;
  }
}

// ================= Launch =================

extern "C" void kernel_launch(void* const* d_in, const int* in_sizes, int n_in,
                              void* d_out, int out_size, void* d_ws, size_t ws_size,
                              hipStream_t stream) {
  const float* x  = (const float*)d_in[0];
  const float* W1 = (const float*)d_in[1];
  const float* b1 = (const float*)d_in[2];
  const float* W2 = (const float*)d_in[3];
  const float* b2 = (const float*)d_in[4];
  const float* W3 = (const float*)d_in[5];
  const float* b3 = (const float*)d_in[6];
  const int* edge = (const int*)d_in[7];

  int N = in_sizes[0] / 128;  // 50000
  int E = in_sizes[7] / 2;    // 800000
  const int* srcp = edge;
  const int* dstp = edge + E;

  char* p = (char*)d_ws;
  auto alloc = [&](size_t bytes) {
    char* r = p;
    p += (bytes + 255) & ~size_t(255);
    return r;
  };
  int NB = (N + 127) >> 7;  // 391 buckets of 128 nodes
  int* partial = (int*)alloc((size_t)CB * 512 * 4);
  int* gstart  = (int*)alloc((size_t)(NB + 1) * 4);
  int* cursor  = (int*)alloc((size_t)NB * 4);
  int* row_ptr = (int*)alloc((size_t)(N + 1) * 4);
  int* packed  = (int*)alloc((size_t)NB * SLOT * 4);  // fixed per-bucket slots
  int* col     = (int*)alloc((size_t)E * 4);
  unsigned short* Wp1 = (unsigned short*)alloc(1536 * 8 * 2);
  unsigned short* Wp2 = (unsigned short*)alloc(1152 * 8 * 2);
  unsigned short* Wp3 = (unsigned short*)alloc(576 * 8 * 2);
  unsigned short* Tb  = (unsigned short*)alloc((size_t)N * 96 * 2);   // t1
  unsigned short* T2b = (unsigned short*)alloc((size_t)N * 96 * 2);   // t2
  unsigned short* T3b = (unsigned short*)alloc((size_t)N * 64 * 2);   // t3, 128-B rows

  int NBIN = (E + EB - 1) / EB;      // 196 binning blocks
  int GB = ((N + 15) / 16 + 3) / 4;  // 782 gemm1 blocks (4 row-tiles each)
  int GB1 = GB / 2;                  // first half with bin+scan (d2)
  int GB2 = GB - GB1;                // second half with build (d3)
  int FB = (N + 63) / 64;            // fused blocks (64 nodes each)

  // 1: bucket count + W pack + cursor zero
  count_pack<<<CB + 14, 256, 0, stream>>>(dstp, partial, E, NB, cursor,
                                          W1, W2, W3, Wp1, Wp2, Wp3);
  // 2: slot-binning + bucket-total scan + gemm1 rows [0, GB1*64)
  bin_scan_gemm1<<<NBIN + 1 + GB1, 256, 0, stream>>>(srcp, dstp, cursor, packed,
                                                     partial, gstart, row_ptr,
                                                     E, NB, NBIN, N, x, Wp1, Tb);
  // 3: per-bucket CSR finalize + gemm1 rows [GB1*64, N)
  build_gemm1<<<NB + GB2, 256, 0, stream>>>(packed, gstart, row_ptr, col, N, NB,
                                            GB1, x, Wp1, Tb);
  // 4: t2 = relu(agg(t1)+b1) @ W2
  fused_agg_gemm<6, 96, 96><<<FB, 256, 0, stream>>>(Tb, row_ptr, col, b1, Wp2, T2b, N);
  // 5: t3 = relu(agg(t2)+b2) @ W3 (row stride 64)
  fused_agg_gemm<3, 64, 40><<<FB, 256, 0, stream>>>(T2b, row_ptr, col, b2, Wp3, T3b, N);
  // 6: out = log_softmax(agg(t3) + b3)
  agg_lsm_bf16<<<(N + 15) / 16, 256, 0, stream>>>(T3b, row_ptr, col, b3, (float*)d_out, N);
}

// Round 14
// 188.316 us; speedup vs baseline: 1.1168x; 1.0015x over previous
//
#include <hip/hip_runtime.h>
#include <math.h>

typedef __attribute__((ext_vector_type(8))) short bf16x8;
typedef __attribute__((ext_vector_type(4))) float f32x4;

__device__ __forceinline__ unsigned short f2bf(float f) {
  unsigned u = __float_as_uint(f);
  u += 0x7fffu + ((u >> 16) & 1u);  // round-to-nearest-even
  return (unsigned short)(u >> 16);
}
__device__ __forceinline__ float bflo(unsigned u) { return __uint_as_float(u << 16); }
__device__ __forceinline__ float bfhi(unsigned u) { return __uint_as_float(u & 0xffff0000u); }

#define ACC8(U)                                           \
  a0 += bflo(U.x); a1 += bfhi(U.x); a2 += bflo(U.y); a3 += bfhi(U.y); \
  a4 += bflo(U.z); a5 += bfhi(U.z); a6 += bflo(U.w); a7 += bfhi(U.w)

// ================= CSR via two-level bucket binning =================
// Buckets of 128 nodes (NB = ceil(N/128) = 391 <= 512). packed edge =
// (d_local<<16)|src, stored in FIXED per-bucket slots (SLOT each) so binning
// needs no global scan first. Requires N <= 65536 — N = 50000 here.

constexpr int CB = 64;      // histogram blocks
constexpr int EB = 4096;    // edges per binning block
constexpr int SLOT = 3072;  // slot capacity per bucket (mean 2048, ~23 sigma)

__global__ __launch_bounds__(256) void count_pack(const int* __restrict__ dst,
                                                  int* __restrict__ partial, int E, int NB,
                                                  int* __restrict__ cursor,
                                                  const float* __restrict__ W1,
                                                  const float* __restrict__ W2,
                                                  const float* __restrict__ W3,
                                                  unsigned short* __restrict__ Wp1,
                                                  unsigned short* __restrict__ Wp2,
                                                  unsigned short* __restrict__ Wp3) {
  int tid = threadIdx.x;
  if (blockIdx.x < CB) {
    __shared__ int bkt[512];
    bkt[tid] = 0;
    bkt[tid + 256] = 0;
    __syncthreads();
    int E4 = E >> 2;
    const int4* d4 = (const int4*)dst;
    for (int i = blockIdx.x * 256 + tid; i < E4; i += CB * 256) {
      int4 d = d4[i];
      atomicAdd(&bkt[d.x >> 7], 1);
      atomicAdd(&bkt[d.y >> 7], 1);
      atomicAdd(&bkt[d.z >> 7], 1);
      atomicAdd(&bkt[d.w >> 7], 1);
    }
    if (blockIdx.x == 0 && tid < (E & 3)) atomicAdd(&bkt[dst[E4 * 4 + tid] >> 7], 1);
    __syncthreads();
    partial[blockIdx.x * 512 + tid] = bkt[tid];
    partial[blockIdx.x * 512 + tid + 256] = bkt[tid + 256];
    return;
  }
  if (blockIdx.x == CB + 13) {  // zero slot cursors
    for (int i = tid; i < NB; i += 256) cursor[i] = 0;
    return;
  }
  int gid = (blockIdx.x - CB) * 256 + tid;
  const float* W;
  unsigned short* Wp;
  int t, NCTT, M, MV;
  if (gid < 1536) {            // W1: 4 ksteps * 6 coltiles * 64 lanes
    W = W1; Wp = Wp1; t = gid; NCTT = 6; M = 96; MV = 96;
  } else if (gid < 2688) {     // W2: 3 * 6 * 64
    W = W2; Wp = Wp2; t = gid - 1536; NCTT = 6; M = 96; MV = 96;
  } else if (gid < 3264) {     // W3: 3 * 3 * 64 (cols >= 40 zero-padded)
    W = W3; Wp = Wp3; t = gid - 2688; NCTT = 3; M = 40; MV = 40;
  } else {
    return;
  }
  int lane = t & 63;
  int frag = t >> 6;
  int s = frag / NCTT;
  int ct = frag - s * NCTT;
  int colv = ct * 16 + (lane & 15);
  int k0 = s * 32 + (lane >> 4) * 8;
  union { unsigned short s[8]; uint4 u; } pk;
#pragma unroll
  for (int j = 0; j < 8; ++j) {
    float v = (colv < MV) ? W[(k0 + j) * M + colv] : 0.f;
    pk.s[j] = f2bf(v);
  }
  ((uint4*)Wp)[t] = pk.u;
}

// gemm1 row-tile worker: block bx covers rows [bx*64, bx*64+64).
__device__ __forceinline__ void gemm1_tile(int bx, int tid, const float* __restrict__ x,
                                           const unsigned short* __restrict__ Wp1,
                                           unsigned short* __restrict__ Tb, int N) {
  int wid = tid >> 6;
  int lane = tid & 63;
  int rt = bx * 4 + wid;
  if (rt * 16 >= N) return;
  int quad = lane >> 4;
  int lm = lane & 15;
  union BU { uint4 u; bf16x8 v; };
  f32x4 acc[6];
#pragma unroll
  for (int c = 0; c < 6; ++c) acc[c] = (f32x4){0.f, 0.f, 0.f, 0.f};
  int row = rt * 16 + lm;
  if (row >= N) row = N - 1;  // safe dup read; epilogue guards rows
  const uint4* wp4 = (const uint4*)Wp1;
#pragma unroll
  for (int s = 0; s < 4; ++s) {
    int k0 = s * 32 + quad * 8;
    const float* Af = x + (size_t)row * 128 + k0;
    float4 x0 = *(const float4*)(Af);
    float4 x1 = *(const float4*)(Af + 4);
    union { unsigned short s[8]; bf16x8 v; } au;
    au.s[0] = f2bf(x0.x); au.s[1] = f2bf(x0.y); au.s[2] = f2bf(x0.z); au.s[3] = f2bf(x0.w);
    au.s[4] = f2bf(x1.x); au.s[5] = f2bf(x1.y); au.s[6] = f2bf(x1.z); au.s[7] = f2bf(x1.w);
#pragma unroll
    for (int c = 0; c < 6; ++c) {
      BU bu;
      bu.u = wp4[(s * 6 + c) * 64 + lane];
      acc[c] = __builtin_amdgcn_mfma_f32_16x16x32_bf16(au.v, bu.v, acc[c], 0, 0, 0);
    }
  }
#pragma unroll
  for (int c = 0; c < 6; ++c) {
    int colv = c * 16 + lm;
#pragma unroll
    for (int r = 0; r < 4; ++r) {
      int orow = rt * 16 + quad * 4 + r;
      if (orow < N) Tb[(size_t)orow * 96 + colv] = f2bf(acc[c][r]);
    }
  }
}

// Dispatch 2: [0,NBIN) LDS-staged binning into fixed slots; block NBIN = scan
// of bucket totals -> gstart; [NBIN+1, ..) first half of gemm1.
__global__ __launch_bounds__(256) void bin_scan_gemm1(
    const int* __restrict__ src, const int* __restrict__ dst, int* __restrict__ cursor,
    int* __restrict__ packed, const int* __restrict__ partial, int* __restrict__ gstart,
    int* __restrict__ row_ptr, int E, int NB, int NBIN, int N,
    const float* __restrict__ x, const unsigned short* __restrict__ Wp1,
    unsigned short* __restrict__ Tb) {
  __shared__ int lcnt[512];
  __shared__ int lstart[512];
  __shared__ int gbase[512];
  __shared__ int cur[512];
  __shared__ int stage[EB];
  int tid = threadIdx.x;
  if (blockIdx.x < (unsigned)NBIN) {
    lcnt[tid] = 0;
    lcnt[tid + 256] = 0;
    __syncthreads();
    int E4 = E >> 2;
    int base4 = blockIdx.x * (EB >> 2);
    int sv[16], dv[16];
    int nv = 0;
#pragma unroll
    for (int j = 0; j < 4; ++j) {
      int idx4 = base4 + j * 256 + tid;
      if (idx4 < E4 && idx4 < base4 + (EB >> 2)) {
        int4 s4 = ((const int4*)src)[idx4];
        int4 d4 = ((const int4*)dst)[idx4];
        sv[j * 4 + 0] = s4.x; dv[j * 4 + 0] = d4.x;
        sv[j * 4 + 1] = s4.y; dv[j * 4 + 1] = d4.y;
        sv[j * 4 + 2] = s4.z; dv[j * 4 + 2] = d4.z;
        sv[j * 4 + 3] = s4.w; dv[j * 4 + 3] = d4.w;
        nv = j * 4 + 4;
      }
    }
#pragma unroll
    for (int i = 0; i < 16; ++i)
      if (i < nv) atomicAdd(&lcnt[dv[i] >> 7], 1);
    bool last = (blockIdx.x == (unsigned)(NBIN - 1));
    int tl = E & 3;
    if (last && tid == 0)
      for (int t = 0; t < tl; ++t) atomicAdd(&lcnt[dst[E4 * 4 + t] >> 7], 1);
    __syncthreads();
    lstart[tid] = lcnt[tid];
    lstart[tid + 256] = lcnt[tid + 256];
    __syncthreads();
    for (int off = 1; off < 512; off <<= 1) {
      int a0 = (tid >= off) ? lstart[tid - off] : 0;
      int i1 = tid + 256;
      int a1 = (i1 >= off) ? lstart[i1 - off] : 0;
      __syncthreads();
      lstart[tid] += a0;
      lstart[i1] += a1;
      __syncthreads();
    }
    int e0 = lstart[tid] - lcnt[tid];
    int e1 = lstart[tid + 256] - lcnt[tid + 256];
    __syncthreads();
    lstart[tid] = e0; cur[tid] = e0;
    lstart[tid + 256] = e1; cur[tid + 256] = e1;
    __syncthreads();
#pragma unroll
    for (int i = 0; i < 16; ++i)
      if (i < nv) {
        int b = dv[i] >> 7;
        int p = atomicAdd(&cur[b], 1);
        stage[p] = ((dv[i] & 127) << 16) | (sv[i] & 0xffff);
      }
    if (last && tid == 0)
      for (int t = 0; t < tl; ++t) {
        int d = dst[E4 * 4 + t], s = src[E4 * 4 + t];
        int p = atomicAdd(&cur[d >> 7], 1);
        stage[p] = ((d & 127) << 16) | (s & 0xffff);
      }
    if (lcnt[tid]) gbase[tid] = atomicAdd(&cursor[tid], lcnt[tid]);
    if (lcnt[tid + 256]) gbase[tid + 256] = atomicAdd(&cursor[tid + 256], lcnt[tid + 256]);
    __syncthreads();
    int meB = lstart[511] + lcnt[511];
    for (int i = tid; i < meB; i += 256) {
      int lo = 0, hi = 511;
      while (lo < hi) {
        int mid = (lo + hi + 1) >> 1;
        if (lstart[mid] <= i) lo = mid; else hi = mid - 1;
      }
      packed[(size_t)lo * SLOT + gbase[lo] + (i - lstart[lo])] = stage[i];
    }
    return;
  }
  if (blockIdx.x == (unsigned)NBIN) {
    int s0 = 0, s1 = 0;
#pragma unroll 8
    for (int i = 0; i < CB; ++i) {
      s0 += partial[i * 512 + tid];
      s1 += partial[i * 512 + tid + 256];
    }
    lcnt[tid] = s0;
    lcnt[tid + 256] = s1;
    __syncthreads();
    for (int off = 1; off < 512; off <<= 1) {
      int a0 = (tid >= off) ? lcnt[tid - off] : 0;
      int i1 = tid + 256;
      int a1 = (i1 >= off) ? lcnt[i1 - off] : 0;
      __syncthreads();
      lcnt[tid] += a0;
      lcnt[i1] += a1;
      __syncthreads();
    }
    int e0 = lcnt[tid] - s0;
    int e1 = lcnt[tid + 256] - s1;
    if (tid < NB) gstart[tid] = e0;
    int b1 = tid + 256;
    if (b1 < NB) gstart[b1] = e1;
    if (tid == 255) gstart[NB] = lcnt[511];
    if (tid == 0) row_ptr[N] = E;
    return;
  }
  gemm1_tile(blockIdx.x - NBIN - 1, tid, x, Wp1, Tb, N);
}

// Dispatch 3: [0,NB) per-bucket CSR finalize; [NB,..) second half of gemm1.
__global__ __launch_bounds__(256) void build_gemm1(const int* __restrict__ packed,
                                                   const int* __restrict__ gstart,
                                                   int* __restrict__ row_ptr,
                                                   int* __restrict__ col, int N, int NB,
                                                   int GB1, const float* __restrict__ x,
                                                   const unsigned short* __restrict__ Wp1,
                                                   unsigned short* __restrict__ Tb) {
  int tid = threadIdx.x;
  if (blockIdx.x >= (unsigned)NB) {
    gemm1_tile(blockIdx.x - NB + GB1, tid, x, Wp1, Tb, N);
    return;
  }
  __shared__ int cnt[128];
  __shared__ int sm[128];
  int b = blockIdx.x;
  int gs = gstart[b], ge = gstart[b + 1];
  int me = ge - gs;
  const int* pslot = packed + (size_t)b * SLOT;
  int node0 = b << 7;
  int RL = N - node0;
  if (RL > 128) RL = 128;
  if (tid < 128) cnt[tid] = 0;
  __syncthreads();
  for (int i = tid; i < me; i += 256) atomicAdd(&cnt[pslot[i] >> 16], 1);
  __syncthreads();
  if (tid < 128) sm[tid] = cnt[tid];
  __syncthreads();
  for (int off = 1; off < 128; off <<= 1) {
    int u = (tid >= off && tid < 128) ? sm[tid - off] : 0;
    __syncthreads();
    if (tid < 128) sm[tid] += u;
    __syncthreads();
  }
  if (tid < 128) {
    int excl = gs + sm[tid] - cnt[tid];
    cnt[tid] = excl;
    if (tid < RL) row_ptr[node0 + tid] = excl;
  }
  __syncthreads();
  for (int i = tid; i < me; i += 256) {
    int pk = pslot[i];
    int p = atomicAdd(&cnt[pk >> 16], 1);
    col[p] = pk & 0xffff;
  }
}

// ================= Fused aggregation + GEMM (degree-sorted) =================
// Block owns 64 nodes. Nodes rank-sorted by degree in-block so each wave's ~6
// concurrent nodes have near-equal degree (kills straggler divergence). Per-
// node accumulation order unchanged -> bit-identical results. Invalid nodes
// key to +inf (sort to end), preserving tail-block guards.

template <int NCT, int MOUT, int MVALID>
__global__ __launch_bounds__(256, 8) void fused_agg_gemm(
    const unsigned short* __restrict__ tin, const int* __restrict__ row_ptr,
    const int* __restrict__ col, const float* __restrict__ bias,
    const unsigned short* __restrict__ Wp, unsigned short* __restrict__ outp, int N) {
  constexpr int LST = 104;   // bf16 units per LDS row
  constexpr int CAP = 1536;  // staged edges (mean 1024, ~16 sigma)
  __shared__ unsigned short sH[64 * LST];
  __shared__ int scol[CAP];
  __shared__ int srp[65];
  __shared__ int sdeg[64];
  __shared__ short sperm[64];  // slot -> local node index (degree-ascending)
  int tid = threadIdx.x;
  int node0 = blockIdx.x * 64;
  int nloc = N - node0;
  if (nloc > 64) nloc = 64;
  if (tid <= nloc) srp[tid] = row_ptr[node0 + tid];
  __syncthreads();
  int gs = srp[0];
  int me = srp[nloc] - gs;
  for (int i = tid; i < me && i < CAP; i += 256) scol[i] = col[gs + i];
  if (tid < 64) sdeg[tid] = (tid < nloc) ? srp[tid + 1] - srp[tid] : 0x7fffffff;
  __syncthreads();
  if (tid < 64) {  // O(64^2) rank sort: unique ranks via index tie-break
    int ki = sdeg[tid];
    int rank = 0;
#pragma unroll 8
    for (int j = 0; j < 64; ++j) {
      int kj = sdeg[j];
      rank += (kj < ki) || (kj == ki && j < tid);
    }
    sperm[rank] = (short)tid;
  }
  __syncthreads();
  bool fits = (me <= CAP);

  // ---- Phase A: slots in degree order; 12 chunks of 8 bf16 per node ----
#pragma unroll
  for (int it = 0; it < 3; ++it) {
    int u = tid + it * 256;
    int sl = u / 12;           // slot (degree-sorted position)
    int c = u - sl * 12;
    int nl = sperm[sl];        // local node for this slot
    if (nl < nloc) {
      int beg = srp[nl] - gs;
      int end = srp[nl + 1] - gs;
      const unsigned short* tc = tin + 8 * c;
      float a0 = 0.f, a1 = 0.f, a2 = 0.f, a3 = 0.f, a4 = 0.f, a5 = 0.f, a6 = 0.f, a7 = 0.f;
      if (fits) {
        int e = beg;
        for (; e + 3 < end; e += 4) {
          int s0 = scol[e], s1 = scol[e + 1], s2 = scol[e + 2], s3 = scol[e + 3];
          uint4 u0 = *(const uint4*)(tc + (size_t)s0 * 96);
          uint4 u1 = *(const uint4*)(tc + (size_t)s1 * 96);
          uint4 u2 = *(const uint4*)(tc + (size_t)s2 * 96);
          uint4 u3 = *(const uint4*)(tc + (size_t)s3 * 96);
          ACC8(u0); ACC8(u1); ACC8(u2); ACC8(u3);
        }
        for (; e < end; ++e) {
          int s0 = scol[e];
          uint4 u4 = *(const uint4*)(tc + (size_t)s0 * 96);
          ACC8(u4);
        }
      } else {  // ~never: degree mass above CAP
        for (int e = beg; e < end; ++e) {
          int s0 = col[gs + e];
          uint4 u4 = *(const uint4*)(tc + (size_t)s0 * 96);
          ACC8(u4);
        }
      }
      const float* b = bias + 8 * c;
      union { unsigned short s[8]; uint4 u; } pk;
      pk.s[0] = f2bf(fmaxf(a0 + b[0], 0.f));
      pk.s[1] = f2bf(fmaxf(a1 + b[1], 0.f));
      pk.s[2] = f2bf(fmaxf(a2 + b[2], 0.f));
      pk.s[3] = f2bf(fmaxf(a3 + b[3], 0.f));
      pk.s[4] = f2bf(fmaxf(a4 + b[4], 0.f));
      pk.s[5] = f2bf(fmaxf(a5 + b[5], 0.f));
      pk.s[6] = f2bf(fmaxf(a6 + b[6], 0.f));
      pk.s[7] = f2bf(fmaxf(a7 + b[7], 0.f));
      *(uint4*)&sH[sl * LST + c * 8] = pk.u;  // store at SLOT row
    }
  }
  __syncthreads();

  // ---- Phase B: MFMA on slot rows; epilogue remaps slot -> node ----
  int wid = tid >> 6;
  int lane = tid & 63;
  int rt16 = wid * 16;
  if (rt16 >= nloc) return;  // invalid slots are all at the end
  int quad = lane >> 4;
  int lm = lane & 15;
  union BU { uint4 u; bf16x8 v; };
  f32x4 acc[NCT];
#pragma unroll
  for (int c = 0; c < NCT; ++c) acc[c] = (f32x4){0.f, 0.f, 0.f, 0.f};
  const uint4* wp4 = (const uint4*)Wp;
#pragma unroll
  for (int s = 0; s < 3; ++s) {
    BU au;
    au.u = *(const uint4*)&sH[(rt16 + lm) * LST + s * 32 + quad * 8];
#pragma unroll
    for (int c = 0; c < NCT; ++c) {
      BU bu;
      bu.u = wp4[(s * NCT + c) * 64 + lane];
      acc[c] = __builtin_amdgcn_mfma_f32_16x16x32_bf16(au.v, bu.v, acc[c], 0, 0, 0);
    }
  }
#pragma unroll
  for (int c = 0; c < NCT; ++c) {
    int colv = c * 16 + lm;
    if (colv >= MVALID) continue;
#pragma unroll
    for (int r = 0; r < 4; ++r) {
      int nl_o = sperm[rt16 + quad * 4 + r];
      if (nl_o < nloc) outp[(size_t)(node0 + nl_o) * MOUT + colv] = f2bf(acc[c][r]);
    }
  }
}

// Layer-3 aggregation (bf16 in, stride 64) + bias + log_softmax, degree-sorted.
// Block = 16 nodes; 16-lane group per node; lanes 0..9 hold 4 classes each.
__global__ __launch_bounds__(256) void agg_lsm_bf16(const unsigned short* __restrict__ t,
                                                    const int* __restrict__ row_ptr,
                                                    const int* __restrict__ col,
                                                    const float* __restrict__ bias,
                                                    float* __restrict__ out, int N) {
  constexpr int CAPL = 1024;  // staged edges (mean 256)
  __shared__ int scol[CAPL];
  __shared__ int srp[17];
  __shared__ int sdeg[16];
  __shared__ short sperm[16];
  int tid = threadIdx.x;
  int node0 = blockIdx.x * 16;
  int nloc = N - node0;
  if (nloc > 16) nloc = 16;
  if (tid <= nloc) srp[tid] = row_ptr[node0 + tid];
  __syncthreads();
  int gs = srp[0];
  int me = srp[nloc] - gs;
  for (int i = tid; i < me && i < CAPL; i += 256) scol[i] = col[gs + i];
  if (tid < 16) sdeg[tid] = (tid < nloc) ? srp[tid + 1] - srp[tid] : 0x7fffffff;
  __syncthreads();
  if (tid < 16) {
    int ki = sdeg[tid];
    int rank = 0;
#pragma unroll
    for (int j = 0; j < 16; ++j) {
      int kj = sdeg[j];
      rank += (kj < ki) || (kj == ki && j < tid);
    }
    sperm[rank] = (short)tid;
  }
  __syncthreads();
  bool fits = (me <= CAPL);

  int sl = tid >> 4;          // slot (degree-sorted)
  int c = tid & 15;           // 0..9 active
  int nl = sperm[sl];         // local node
  bool act = (c < 10) && (nl < nloc);
  int ceff = (c < 10) ? c : 0;
  const unsigned short* tc = t + 4 * ceff;
  float v0 = 0.f, v1 = 0.f, v2 = 0.f, v3 = 0.f;
  if (act) {
    int beg = srp[nl] - gs;
    int end = srp[nl + 1] - gs;
    if (fits) {
      int e = beg;
      for (; e + 3 < end; e += 4) {
        int s0 = scol[e], s1 = scol[e + 1], s2 = scol[e + 2], s3 = scol[e + 3];
        uint2 u = *(const uint2*)(tc + (size_t)s0 * 64);
        uint2 w = *(const uint2*)(tc + (size_t)s1 * 64);
        uint2 y = *(const uint2*)(tc + (size_t)s2 * 64);
        uint2 z = *(const uint2*)(tc + (size_t)s3 * 64);
        v0 += bflo(u.x); v1 += bfhi(u.x); v2 += bflo(u.y); v3 += bfhi(u.y);
        v0 += bflo(w.x); v1 += bfhi(w.x); v2 += bflo(w.y); v3 += bfhi(w.y);
        v0 += bflo(y.x); v1 += bfhi(y.x); v2 += bflo(y.y); v3 += bfhi(y.y);
        v0 += bflo(z.x); v1 += bfhi(z.x); v2 += bflo(z.y); v3 += bfhi(z.y);
      }
      for (; e < end; ++e) {
        int s0 = scol[e];
        uint2 u = *(const uint2*)(tc + (size_t)s0 * 64);
        v0 += bflo(u.x); v1 += bfhi(u.x); v2 += bflo(u.y); v3 += bfhi(u.y);
      }
    } else {
      for (int e = beg; e < end; ++e) {
        int s0 = col[gs + e];
        uint2 u = *(const uint2*)(tc + (size_t)s0 * 64);
        v0 += bflo(u.x); v1 += bfhi(u.x); v2 += bflo(u.y); v3 += bfhi(u.y);
      }
    }
  }
  const float* bb = bias + 4 * ceff;
  v0 += bb[0]; v1 += bb[1]; v2 += bb[2]; v3 += bb[3];
  float m = act ? fmaxf(fmaxf(v0, v1), fmaxf(v2, v3)) : -__builtin_inff();
#pragma unroll
  for (int off = 8; off; off >>= 1) m = fmaxf(m, __shfl_xor(m, off, 64));
  float ex = act ? (__expf(v0 - m) + __expf(v1 - m) + __expf(v2 - m) + __expf(v3 - m)) : 0.f;
#pragma unroll
  for (int off = 8; off; off >>= 1) ex += __shfl_xor(ex, off, 64);
  if (act) {
    int node = node0 + nl;
    float l = m + __logf(ex);
    float* o = out + (size_t)node * 40 + 4 * c;
    o[0] = v0 - l; o[1] = v1 - l; o[2] = v2 - l; o[3] = v3 - l;
  }
}

// ================= Launch =================

extern "C" void kernel_launch(void* const* d_in, const int* in_sizes, int n_in,
                              void* d_out, int out_size, void* d_ws, size_t ws_size,
                              hipStream_t stream) {
  const float* x  = (const float*)d_in[0];
  const float* W1 = (const float*)d_in[1];
  const float* b1 = (const float*)d_in[2];
  const float* W2 = (const float*)d_in[3];
  const float* b2 = (const float*)d_in[4];
  const float* W3 = (const float*)d_in[5];
  const float* b3 = (const float*)d_in[6];
  const int* edge = (const int*)d_in[7];

  int N = in_sizes[0] / 128;  // 50000
  int E = in_sizes[7] / 2;    // 800000
  const int* srcp = edge;
  const int* dstp = edge + E;

  char* p = (char*)d_ws;
  auto alloc = [&](size_t bytes) {
    char* r = p;
    p += (bytes + 255) & ~size_t(255);
    return r;
  };
  int NB = (N + 127) >> 7;  // 391 buckets of 128 nodes
  int* partial = (int*)alloc((size_t)CB * 512 * 4);
  int* gstart  = (int*)alloc((size_t)(NB + 1) * 4);
  int* cursor  = (int*)alloc((size_t)NB * 4);
  int* row_ptr = (int*)alloc((size_t)(N + 1) * 4);
  int* packed  = (int*)alloc((size_t)NB * SLOT * 4);  // fixed per-bucket slots
  int* col     = (int*)alloc((size_t)E * 4);
  unsigned short* Wp1 = (unsigned short*)alloc(1536 * 8 * 2);
  unsigned short* Wp2 = (unsigned short*)alloc(1152 * 8 * 2);
  unsigned short* Wp3 = (unsigned short*)alloc(576 * 8 * 2);
  unsigned short* Tb  = (unsigned short*)alloc((size_t)N * 96 * 2);   // t1
  unsigned short* T2b = (unsigned short*)alloc((size_t)N * 96 * 2);   // t2
  unsigned short* T3b = (unsigned short*)alloc((size_t)N * 64 * 2);   // t3, 128-B rows

  int NBIN = (E + EB - 1) / EB;      // 196 binning blocks
  int GB = ((N + 15) / 16 + 3) / 4;  // 782 gemm1 blocks (4 row-tiles each)
  int GB1 = GB / 2;                  // first half with bin+scan (d2)
  int GB2 = GB - GB1;                // second half with build (d3)
  int FB = (N + 63) / 64;            // fused blocks (64 nodes each)

  // 1: bucket count + W pack + cursor zero
  count_pack<<<CB + 14, 256, 0, stream>>>(dstp, partial, E, NB, cursor,
                                          W1, W2, W3, Wp1, Wp2, Wp3);
  // 2: slot-binning + bucket-total scan + gemm1 rows [0, GB1*64)
  bin_scan_gemm1<<<NBIN + 1 + GB1, 256, 0, stream>>>(srcp, dstp, cursor, packed,
                                                     partial, gstart, row_ptr,
                                                     E, NB, NBIN, N, x, Wp1, Tb);
  // 3: per-bucket CSR finalize + gemm1 rows [GB1*64, N)
  build_gemm1<<<NB + GB2, 256, 0, stream>>>(packed, gstart, row_ptr, col, N, NB,
                                            GB1, x, Wp1, Tb);
  // 4: t2 = relu(agg(t1)+b1) @ W2
  fused_agg_gemm<6, 96, 96><<<FB, 256, 0, stream>>>(Tb, row_ptr, col, b1, Wp2, T2b, N);
  // 5: t3 = relu(agg(t2)+b2) @ W3 (row stride 64)
  fused_agg_gemm<3, 64, 40><<<FB, 256, 0, stream>>>(T2b, row_ptr, col, b2, Wp3, T3b, N);
  // 6: out = log_softmax(agg(t3) + b3)
  agg_lsm_bf16<<<(N + 15) / 16, 256, 0, stream>>>(T3b, row_ptr, col, b3, (float*)d_out, N);
}